// Round 14
// baseline (307.394 us; speedup 1.0000x reference)
//
#include <hip/hip_runtime.h>
#include <hip/hip_fp16.h>
#include <stdint.h>

// ResonanceLayer: routed einsum -> resonance irfft (x-pair packed, frames to
// scratch) -> OLA+transpose+norm -> upsample*threefry-noise -> 65536-pt FFT
// convolution with complex-packed res spectra -> softmax-deformation mix ->
// tanh(gain*x) summed over resonators.
//
// Round-26: LDS bank-conflict reduction (conflicts = ~20% of k_conv cycles).
// (a) Fh snapshot interleaved by quad: thread t quad cc at Fh4[cc*256+t]
//     (was t*16 -> 64B stride -> ~8-way on every b128 Fh op; now start bank
//     4t mod 32, uniform). Private re-layout, zero cost.
// (b) RPW 328 -> 340 (=20 mod 32, still 16B-aligned groups): P3/P2 b128
//     group ops' row starts become {0,20,8,28,16,4,24,12} -- distinct,
//     spacing>=4 -> conflict-free per 8 rows (was 4-way at stride-8 starts).
// LDS k_conv 39424->40192B, still exactly 4 blk/CU; others >=6 blk/CU.
// Rest identical to r25 (305.2us).

#define PI_F     3.14159265358979323846f
#define TWOPI_F  6.28318530717958647692f
#define UNIT64K  (TWOPI_F/65536.0f)
#define UNIT2K   (TWOPI_F/2048.0f)
#define SCALE64K (1.0f/65536.0f)
#define SKP(i)   ((i) + 4*((i) >> 4))    // block-FFT pad: 16B-aligned groups
#define RPW 340                          // block-FFT row pitch (=20 mod 32)

__device__ __forceinline__ float2 cmul(float2 a, float2 b){
  return make_float2(a.x*b.x - a.y*b.y, a.x*b.y + a.y*b.x);
}

__device__ __forceinline__ float2 twid(uint32_t e, float unit, float sign){
  float ang = (float)e * unit;
  float sn, cn;
  __sincosf(ang, &sn, &cn);
  return make_float2(cn, sign*sn);
}

__device__ __forceinline__ uint32_t rotl32(uint32_t v, int r){
  return (v << r) | (v >> (32 - r));
}

// Threefry-2x32, key = (0, 123)
__device__ __forceinline__ void threefry2x32(uint32_t c0, uint32_t c1,
                                             uint32_t& o0, uint32_t& o1){
  const uint32_t k0 = 0u, k1 = 123u;
  const uint32_t k2 = 0x1BD11BDAu ^ k0 ^ k1;
  const uint32_t ks[3] = {k0, k1, k2};
  uint32_t x0 = c0 + k0, x1 = c1 + k1;
#pragma unroll
  for (int i = 0; i < 5; i++){
    if ((i & 1) == 0){
      x0 += x1; x1 = rotl32(x1,13); x1 ^= x0;
      x0 += x1; x1 = rotl32(x1,15); x1 ^= x0;
      x0 += x1; x1 = rotl32(x1,26); x1 ^= x0;
      x0 += x1; x1 = rotl32(x1, 6); x1 ^= x0;
    } else {
      x0 += x1; x1 = rotl32(x1,17); x1 ^= x0;
      x0 += x1; x1 = rotl32(x1,29); x1 ^= x0;
      x0 += x1; x1 = rotl32(x1,16); x1 ^= x0;
      x0 += x1; x1 = rotl32(x1,24); x1 ^= x0;
    }
    x0 += ks[(i+1)%3];
    x1 += ks[(i+2)%3] + (uint32_t)(i+1);
  }
  o0 = x0; o1 = x1;
}

__device__ __forceinline__ float jax_noise(uint32_t p){
  uint32_t b0, b1;
  threefry2x32(0u, p, b0, b1);
  uint32_t bits = b0 ^ b1;
  float u = __uint_as_float((bits >> 9) | 0x3f800000u) - 1.0f;
  return fmaxf(-1.0f, u*2.0f - 1.0f);
}

__device__ __forceinline__ void interp128(int t, int& lo, int& hi, float& w){
  float posf = ((float)t + 0.5f) * (1.0f/256.0f) - 0.5f;
  posf = fminf(fmaxf(posf, 0.0f), 127.0f);
  lo = (int)posf;
  hi = lo + 1; if (hi > 127) hi = 127;
  w = posf - (float)lo;
}

// ------------------------- radix-16 register FFT ---------------------------
__device__ __forceinline__ __half2 u2h(uint32_t u){
  union { uint32_t u; __half2 h; } x; x.u = u; return x.h;
}
__device__ __forceinline__ uint32_t h2u(__half2 h){
  union { uint32_t u; __half2 h; } x; x.h = h; return x.u;
}
__device__ __forceinline__ constexpr int sw4(int k){ return ((k & 3) << 2) | (k >> 2); }
__device__ __forceinline__ constexpr int br4(int x){
  return ((x & 1) << 3) | ((x & 2) << 1) | ((x & 4) >> 1) | ((x & 8) >> 3);
}

// u *= (c + i s)
__device__ __forceinline__ void cws(float2& u, const float c, const float s){
  const float x = u.x*c - u.y*s;
  u.y = u.x*s + u.y*c;
  u.x = x;
}
__device__ __forceinline__ void cwv(float2& u, const float2 w){
  const float x = u.x*w.x - u.y*w.y;
  u.y = u.x*w.y + u.y*w.x;
  u.x = x;
}

// radix-4 butterfly, sgn = -1 fwd (e^{-i}), +1 inv (e^{+i})
__device__ __forceinline__ void dft4(float2& a, float2& b, float2& c, float2& d,
                                     const float sgn){
  float2 t0 = make_float2(a.x + c.x, a.y + c.y);
  float2 t1 = make_float2(a.x - c.x, a.y - c.y);
  float2 t2 = make_float2(b.x + d.x, b.y + d.y);
  float2 t3 = make_float2(b.x - d.x, b.y - d.y);
  float2 i3 = make_float2(-sgn*t3.y, sgn*t3.x);   // sgn*i*t3
  a = make_float2(t0.x + t2.x, t0.y + t2.y);      // y0
  c = make_float2(t0.x - t2.x, t0.y - t2.y);      // y2
  b = make_float2(t1.x + i3.x, t1.y + i3.y);      // y1
  d = make_float2(t1.x - i3.x, t1.y - i3.y);      // y3
}

// W16 twiddles at positions p: j(p) = (p>>2)*(p&3) — identical for dft16/dft16b
#define DFT16_TW(d, sgn) do { \
  const float C1_ = 0.92387953251128674f, S1_ = 0.38268343236508978f; \
  const float C2_ = 0.70710678118654752f; \
  cws(d[5],  C1_,  (sgn)*S1_); \
  cws(d[6],  C2_,  (sgn)*C2_); \
  cws(d[7],  S1_,  (sgn)*C1_); \
  cws(d[9],  C2_,  (sgn)*C2_); \
  cws(d[10], 0.0f, (sgn)); \
  cws(d[11], -C2_, (sgn)*C2_); \
  cws(d[13], S1_,  (sgn)*C1_); \
  cws(d[14], -C2_, (sgn)*C2_); \
  cws(d[15], -C1_, -(sgn)*S1_); \
} while(0)

// 16-pt DFT: input x[n] at d[n] natural; output X[k] at d[sw4(k)]
__device__ __forceinline__ void dft16(float2* d, const float sgn){
#pragma unroll
  for (int nb = 0; nb < 4; nb++) dft4(d[nb], d[nb+4], d[nb+8], d[nb+12], sgn);
  DFT16_TW(d, sgn);
#pragma unroll
  for (int ka = 0; ka < 4; ka++) dft4(d[4*ka], d[4*ka+1], d[4*ka+2], d[4*ka+3], sgn);
}
// 16-pt DFT, swapped-input variant: input x[n] at d[sw4(n)]; output X[k] at d[k]
__device__ __forceinline__ void dft16b(float2* d, const float sgn){
#pragma unroll
  for (int nb = 0; nb < 4; nb++) dft4(d[4*nb], d[4*nb+1], d[4*nb+2], d[4*nb+3], sgn);
  DFT16_TW(d, sgn);
#pragma unroll
  for (int ka = 0; ka < 4; ka++) dft4(d[ka], d[ka+4], d[ka+8], d[ka+12], sgn);
}

// P1 fwd: per (row, L): 16-DFT over high digit H (strided cells L+20H),
// twiddle W_256^{L*k1}, write slot(L+16k1) = cell L+20k1.
__device__ __forceinline__ void pass1_fwd(__half2* buf, const float2* twl, const int t){
  const int row = t >> 4, L = t & 15;
  __half2* BR = buf + row*RPW;
  float2 d[16];
#pragma unroll
  for (int H = 0; H < 16; H++) d[H] = __half22float2(BR[L + 20*H]);
  dft16(d, -1.0f);
#pragma unroll
  for (int k1 = 0; k1 < 16; k1++){
    float2 y = d[sw4(k1)];
    cwv(y, twl[(L*k1) & 255]);
    BR[L + 20*k1] = __floats2half2_rn(y.x, y.y);
  }
}

// ---------------- routed einsum + output1 + softmax(deformations) ----------
__global__ void k_routed(const float* __restrict__ ctrl, const float* __restrict__ defm,
                         const float* __restrict__ router,
                         float* __restrict__ w_routed, float* __restrict__ w_sm,
                         float* __restrict__ out1){
  int idx = blockIdx.x*blockDim.x + threadIdx.x;
  if (idx < 32768){
    int f = idx & 127, r = (idx >> 7) & 31, be = idx >> 12;
    float acc = 0.0f;
#pragma unroll
    for (int c = 0; c < 16; c++)
      acc += ctrl[(be*16 + c)*128 + f] * router[c*32 + r];
    w_routed[idx] = acc;
    out1[idx] = acc;
  } else if (idx < 32768 + 1024){
    int j = idx - 32768;
    int f = j & 127, be = j >> 7;
    float v[4];
#pragma unroll
    for (int x = 0; x < 4; x++)
      v[x] = defm[(be*4 + x)*128 + f] + (x == 0 ? 1.0f : 0.0f);
    float mx = fmaxf(fmaxf(v[0], v[1]), fmaxf(v[2], v[3]));
    float s = 0.0f;
#pragma unroll
    for (int x = 0; x < 4; x++){ v[x] = expf(v[x] - mx); s += v[x]; }
#pragma unroll
    for (int x = 0; x < 4; x++) w_sm[(be*4 + x)*128 + f] = v[x]/s;
  }
}

// ---- param precompute: per (r,k,x): (a cos, a sin, log_dc) ----------------
__global__ void k_prep(const float* __restrict__ amp, const float* __restrict__ phase,
                       const float* __restrict__ decay, float4* __restrict__ pql){
  const int idx = blockIdx.x*256 + threadIdx.x;
  if (idx >= 131200) return;           // 32 r * 1025 k * 4 x
  float a  = fabsf(amp[idx]);
  float ph = tanhf(phase[idx]) * PI_F;
  float sg = 1.0f / (1.0f + expf(-decay[idx]));
  float dc = 0.5f + 0.45f * sg;
  float L  = logf(dc + 1e-12f);
  float sn, cs;
  sincosf(ph, &sn, &cs);
  pql[idx] = make_float4(a*cs, a*sn, L, 0.0f);
}

// ---- resonance frames: packed complex irfft(2048) of x-pairs + hann -------
__global__ void k_frames(const float4* __restrict__ pql, float2* __restrict__ w_fr){
  const int wg = blockIdx.x;          // (r,p,f)
  const int f = wg & 31;
  const int rp = wg >> 5;             // r*2 + p
  const int p = rp & 1;
  const int r = rp >> 1;
  const int t = threadIdx.x;
  __shared__ float2 buf[2048];
  __shared__ float2 twl2[1024];

  for (int i = t; i < 1024; i += 256)
    twl2[i] = twid((uint32_t)i, UNIT2K, +1.0f);

  const float fp1 = (float)(f + 1);
  for (int k = t; k <= 1024; k += 256){
    float2 S[2];
#pragma unroll
    for (int d = 0; d < 2; d++){
      const int x = 2*p + d;
      const float4 q = pql[(r*1025 + k)*4 + x];
      const float e = __expf(q.z * fp1);
      float re = e*q.x, im = e*q.y;
      if (k == 0 || k == 1024) im = 0.0f;
      S[d] = make_float2(re, im);
    }
    buf[__brev((uint32_t)k) >> 21] =
        make_float2(S[0].x - S[1].y, S[0].y + S[1].x);
    if (k >= 1 && k <= 1023)
      buf[__brev((uint32_t)(2048 - k)) >> 21] =
          make_float2(S[0].x + S[1].y, -S[0].y + S[1].x);
  }
  __syncthreads();
  for (int s = 10; s >= 0; s--){
    const int ls = 10 - s;
    const int hl = 1 << ls;
    for (int bi = t; bi < 1024; bi += 256){
      const int g = bi >> ls, j = bi & (hl - 1);
      const int i0 = g*2*hl + j, i1 = i0 + hl;
      float2 pp = buf[i0], qq = buf[i1];
      float2 w = twl2[j << s];
      float2 v = cmul(qq, w);
      buf[i0] = make_float2(pp.x+v.x, pp.y+v.y);
      buf[i1] = make_float2(pp.x-v.x, pp.y-v.y);
    }
    __syncthreads();
  }
  float2* O = w_fr + (size_t)wg*2048;
  for (int u = t; u < 2048; u += 256){
    float hann = 0.5f - 0.5f*cosf(TWOPI_F * (float)u / 2048.0f);
    float sc = (1.0f/2048.0f) * hann;
    O[u] = make_float2(buf[u].x*sc, buf[u].y*sc);
  }
}

// ---- OLA + transpose + sum-of-squares ------------------------------------
__global__ void k_ola(const float2* __restrict__ w_fr, float* __restrict__ w_resT,
                      float* __restrict__ w_sumsq){
  const int wg = blockIdx.x;           // rp*8 + cq
  const int cq = wg & 7;
  const int rp = wg >> 3;
  const int c0 = cq*32;
  const int r = rp >> 1, p = rp & 1;
  const int ch0 = r*4 + p*2;
  const int t = threadIdx.x;
  __shared__ float tx[32][129], ty[32][129];
  __shared__ float red[2][256];
  const float2* F = w_fr + (size_t)rp*32*2048;
  float acc0 = 0.0f, acc1 = 0.0f;
#pragma unroll
  for (int it = 0; it < 16; it++){
    const int idx = it*256 + t;        // m*32 + c'  (time-ordered reads)
    const int cp = idx & 31, m = idx >> 5;
    const int n = c0 + cp + 256*m;
    const int f = n >> 10, u = n & 1023;
    float2 a = F[(size_t)f*2048 + u];
    float vx = a.x, vy = a.y;
    if (f > 0){
      float2 b = F[(size_t)(f-1)*2048 + u + 1024];
      vx += b.x; vy += b.y;
    }
    tx[cp][m] = vx; ty[cp][m] = vy;
    acc0 += vx*vx; acc1 += vy*vy;
  }
  red[0][t] = acc0; red[1][t] = acc1;
  __syncthreads();
#pragma unroll
  for (int it = 0; it < 16; it++){
    const int idx = it*256 + t;        // c'*128 + m  (contiguous writes)
    const int m = idx & 127, cp = idx >> 7;
    w_resT[(size_t)ch0*32768 + (size_t)(c0+cp)*128 + m]     = tx[cp][m];
    w_resT[(size_t)(ch0+1)*32768 + (size_t)(c0+cp)*128 + m] = ty[cp][m];
  }
  for (int off = 128; off > 0; off >>= 1){
    __syncthreads();
    if (t < off){ red[0][t] += red[0][t+off]; red[1][t] += red[1][t+off]; }
  }
  if (t == 0){
    atomicAdd(&w_sumsq[ch0],     red[0][0]);
    atomicAdd(&w_sumsq[ch0 + 1], red[1][0]);
  }
}

// ---------------- invnorm from sumsq (1 tiny block) ------------------------
__global__ void k_norm(const float* __restrict__ w_sumsq, float* __restrict__ w_invnorm){
  const int s = threadIdx.x;
  if (s < 128) w_invnorm[s] = 1.0f/(sqrtf(w_sumsq[s]) + 1e-8f);
}

// --------- forward comb (radix-16^2 registers), mirror of k_invA_w ---------
__global__ __launch_bounds__(256, 4)
void k_fwdA(const int mode, const float* __restrict__ w_resT,
            const float* __restrict__ w_invnorm,
            const float* __restrict__ w_routed,
            __half2* __restrict__ outh){
  const int wg = blockIdx.x;
  const int cq = wg & 15;
  const int sig = wg >> 4;
  const int t = threadIdx.x;
  const int cc = t >> 4;
  const int c  = cq*16 + cc;
  __shared__ alignas(16) __half2 buf[16*RPW];

  // ---- P1: inputs direct to regs, dft16(-1) over mH, chained twiddle -----
  {
    const int mL = t & 15;
    float2 d[16];
    if (mode == 0){
      const int rr = sig >> 1, pq = sig & 1;
      const int ch0 = rr*4 + pq*2;
      const float inv0 = w_invnorm[ch0], inv1 = w_invnorm[ch0+1];
      const float* X0 = w_resT + (size_t)ch0*32768 + (size_t)c*128;
      const float* X1 = w_resT + (size_t)(ch0+1)*32768 + (size_t)c*128;
#pragma unroll
      for (int mH = 0; mH < 8; mH++){
        const int m = mL + 16*mH;
        d[mH] = make_float2(X0[m]*inv0, X1[m]*inv1);
      }
#pragma unroll
      for (int mH = 8; mH < 16; mH++) d[mH] = make_float2(0.0f, 0.0f);
    } else {
      const float* rp = w_routed + sig*128;
#pragma unroll
      for (int mH = 0; mH < 8; mH++){
        const int m = mL + 16*mH;
        const int n = c + 256*m;
        int lo, hi; float w;
        interp128(n, lo, hi, w);
        float rv = rp[lo]*(1.0f - w) + rp[hi]*w;
        d[mH] = make_float2(rv * jax_noise((uint32_t)sig*32768u + (uint32_t)n), 0.0f);
      }
#pragma unroll
      for (int mH = 8; mH < 16; mH++) d[mH] = make_float2(0.0f, 0.0f);
    }
    dft16(d, -1.0f);                   // T[rhoL] at d[sw4(rhoL)]
    const float2 wstep = twid((uint32_t)(c + 256*mL) & 0xFFFFu, UNIT64K, -1.0f);
    float2 w = wstep;
    __half2* BR = buf + cc*RPW;
    BR[mL] = __floats2half2_rn(d[0].x, d[0].y);       // rhoL=0 (w^0)
#pragma unroll
    for (int rl = 1; rl < 16; rl++){
      float2 y = d[sw4(rl)];
      cwv(y, w);
      w = cmul(w, wstep);
      BR[20*rl + mL] = __floats2half2_rn(y.x, y.y);
    }
  }
  __syncthreads();
  // ---- P2: consecutive reads, dft16(-1) over mL, post-twiddle, store -----
  {
    const int rl = t & 15;             // rhoL
    const __half2* BG = buf + cc*RPW + 20*rl;
    float2 v[16];
#pragma unroll
    for (int q4 = 0; q4 < 4; q4++){
      const uint4 ld = *reinterpret_cast<const uint4*>(BG + 4*q4);
      v[4*q4+0] = __half22float2(u2h(ld.x));
      v[4*q4+1] = __half22float2(u2h(ld.y));
      v[4*q4+2] = __half22float2(u2h(ld.z));
      v[4*q4+3] = __half22float2(u2h(ld.w));
    }
    dft16(v, -1.0f);                   // U[rhoH] at v[sw4(rhoH)]
    const float2 wstep = twid((uint32_t)(16*c) & 0xFFFFu, UNIT64K, -1.0f);
    float2 w = wstep;
    __half2 y[16];
    y[0] = __floats2half2_rn(v[0].x, v[0].y);         // rhoH=0 (sw4(0)=0)
#pragma unroll
    for (int rh = 1; rh < 16; rh++){
      float2 u = v[sw4(rh)];
      cwv(u, w);
      w = cmul(w, wstep);
      y[rh] = __floats2half2_rn(u.x, u.y);
    }
    // store at positions j in group 16*br4(rl): value y[br4(j)]
    uint4* O4 = reinterpret_cast<uint4*>(
        outh + (size_t)sig*65536 + (size_t)c*256 + 16*br4(rl));
#pragma unroll
    for (int q4 = 0; q4 < 4; q4++){
      uint4 st;
      st.x = h2u(y[br4(4*q4+0)]);
      st.y = h2u(y[br4(4*q4+1)]);
      st.z = h2u(y[br4(4*q4+2)]);
      st.w = h2u(y[br4(4*q4+3)]);
      O4[q4] = st;
    }
  }
}

// ------- forward block stages (radix-16^2) for res spectra -----------------
__global__ __launch_bounds__(256, 4)
void k_fwdB(const __half2* __restrict__ spech, __half2* __restrict__ resp_t){
  const int wg = blockIdx.x;
  const int mq = wg & 15;
  const int sig = wg >> 4;
  const int m16 = mq*16;
  const int t = threadIdx.x;
  __shared__ alignas(16) __half2 buf[16*RPW];
  __shared__ float2 twl[256];
  twl[t] = twid((uint32_t)t << 8, UNIT64K, -1.0f);
  const __half2* base = spech + (size_t)sig*65536;
  {
    const int mm = t & 15, q = t >> 4;
    __half2* BR = buf + mm*RPW;
#pragma unroll
    for (int i = 0; i < 16; i++)
      BR[20*i + q] = base[(size_t)(16*i + q)*256 + m16 + mm];
  }
  __syncthreads();
  pass1_fwd(buf, twl, t);
  __syncthreads();
  {
    const int k1 = t >> 4, row = t & 15;
    __half2* BG = buf + row*RPW + 20*k1;
    float2 v[16];
#pragma unroll
    for (int cc = 0; cc < 4; cc++){
      const uint4 ld = *reinterpret_cast<const uint4*>(BG + 4*cc);
      v[4*cc+0] = __half22float2(u2h(ld.x));
      v[4*cc+1] = __half22float2(u2h(ld.y));
      v[4*cc+2] = __half22float2(u2h(ld.z));
      v[4*cc+3] = __half22float2(u2h(ld.w));
    }
    dft16(v, -1.0f);
    uint4* O4 = reinterpret_cast<uint4*>(resp_t + (((size_t)sig*16 + mq)*256 + t)*16);
#pragma unroll
    for (int cc = 0; cc < 4; cc++){
      uint4 st;
      st.x = h2u(__floats2half2_rn(v[4*cc+0].x, v[4*cc+0].y));
      st.y = h2u(__floats2half2_rn(v[4*cc+1].x, v[4*cc+1].y));
      st.z = h2u(__floats2half2_rn(v[4*cc+2].x, v[4*cc+2].y));
      st.w = h2u(__floats2half2_rn(v[4*cc+3].x, v[4*cc+3].y));
      O4[cc] = st;
    }
  }
}

// ---- FUSED: ru fwd (radix-16^2) + BOTH products + inverses, 1 blk/(g,mq) --
// Forward spectrum Z parked in LDS Fh, quad-interleaved (Fh4[cc*256+t]).
// remap=1 (G=256): slice-major XCD-affine block order for resp_t L2 reuse.
__global__ __launch_bounds__(256, 4)
void k_conv(const __half2* __restrict__ ruspec,
            const __half2* __restrict__ resp_t,
            __half2* __restrict__ chunkbuf, const int gbase, const int remap){
  const int wg = blockIdx.x;
  int mq, gl;
  if (remap){
    // id = sOuter*64 + be*8 + xcd ; s = sOuter*8 + xcd = mq*32 + r
    const int xcd = wg & 7, be = (wg >> 3) & 7, sOuter = wg >> 6;
    const int s = sOuter*8 + xcd;
    mq = s >> 5;
    const int r8 = s & 31;
    gl = be*32 + r8;                   // gbase = 0 in this mode
  } else {
    mq = wg & 15;
    gl = wg >> 4;
  }
  const int g = gbase + gl;
  const int r = g & 31;
  const int m16 = mq*16;
  const int t = threadIdx.x;
  __shared__ alignas(16) __half2 buf[16*RPW];
  __shared__ alignas(16) __half2 Fh[4096];
  __shared__ float2 twl[256];
  twl[t] = twid((uint32_t)t << 8, UNIT64K, -1.0f);
  uint4* Fh4 = reinterpret_cast<uint4*>(Fh);

  // staging (once): thread t owns slot c = t; 4x uint4 contiguous
  {
    const uint4* A4 = reinterpret_cast<const uint4*>(
        ruspec + (size_t)g*65536 + (size_t)t*256 + m16);
    uint4 a0 = A4[0], a1 = A4[1], a2 = A4[2], a3 = A4[3];
    const int cs = SKP(t);
    uint32_t w[16];
    w[0]=a0.x; w[1]=a0.y; w[2]=a0.z; w[3]=a0.w;
    w[4]=a1.x; w[5]=a1.y; w[6]=a1.z; w[7]=a1.w;
    w[8]=a2.x; w[9]=a2.y; w[10]=a2.z; w[11]=a2.w;
    w[12]=a3.x; w[13]=a3.y; w[14]=a3.z; w[15]=a3.w;
#pragma unroll
    for (int mm = 0; mm < 16; mm++)
      buf[mm*RPW + cs] = u2h(w[mm]);
  }
  __syncthreads();                       // (1)
  pass1_fwd(buf, twl, t);
  __syncthreads();                       // (2)
  const int k1 = t >> 4, row = t & 15;
  __half2* BG = buf + row*RPW + 20*k1;
  // ---- P3a: fwd dft16 once; snapshot Z->Fh; product p0; inv-low; tw ------
  {
    float2 v[16];
#pragma unroll
    for (int cc = 0; cc < 4; cc++){
      const uint4 ld = *reinterpret_cast<const uint4*>(BG + 4*cc);
      v[4*cc+0] = __half22float2(u2h(ld.x));
      v[4*cc+1] = __half22float2(u2h(ld.y));
      v[4*cc+2] = __half22float2(u2h(ld.z));
      v[4*cc+3] = __half22float2(u2h(ld.w));
    }
    const uint4* Bt0 = reinterpret_cast<const uint4*>(
        resp_t + (((size_t)(r*2 + 0)*16 + mq)*256 + t)*16);
    uint4 b0 = Bt0[0], b1 = Bt0[1], b2 = Bt0[2], b3 = Bt0[3];
    dft16(v, -1.0f);                    // Z[k2] at v[sw4(k2)]
    // park Z in Fh, quad-interleaved: start bank 4t mod 32 (uniform)
#pragma unroll
    for (int cc = 0; cc < 4; cc++){
      uint4 st;
      st.x = h2u(__floats2half2_rn(v[4*cc+0].x, v[4*cc+0].y));
      st.y = h2u(__floats2half2_rn(v[4*cc+1].x, v[4*cc+1].y));
      st.z = h2u(__floats2half2_rn(v[4*cc+2].x, v[4*cc+2].y));
      st.w = h2u(__floats2half2_rn(v[4*cc+3].x, v[4*cc+3].y));
      Fh4[cc*256 + t] = st;
    }
    uint32_t bw[16];
    bw[0]=b0.x; bw[1]=b0.y; bw[2]=b0.z; bw[3]=b0.w;
    bw[4]=b1.x; bw[5]=b1.y; bw[6]=b1.z; bw[7]=b1.w;
    bw[8]=b2.x; bw[9]=b2.y; bw[10]=b2.z; bw[11]=b2.w;
    bw[12]=b3.x; bw[13]=b3.y; bw[14]=b3.z; bw[15]=b3.w;
#pragma unroll
    for (int pp = 0; pp < 16; pp++){
      const float2 b = __half22float2(u2h(bw[pp]));
      const float zx = v[pp].x, zy = v[pp].y;
      v[pp] = make_float2((zx*b.x - zy*b.y)*SCALE64K,
                          (zx*b.y + zy*b.x)*SCALE64K);
    }
    dft16b(v, +1.0f);                   // m[n2] at v[n2]
    __half2 h[16];
#pragma unroll
    for (int n2 = 0; n2 < 16; n2++){    // conj twiddle W_256^{-n2*k1}
      float2 m = v[n2];
      const float2 w = twl[(n2*k1) & 255];
      const float x = m.x*w.x + m.y*w.y;
      m.y = -m.x*w.y + m.y*w.x;
      m.x = x;
      h[n2] = __floats2half2_rn(m.x, m.y);
    }
#pragma unroll
    for (int cc = 0; cc < 4; cc++){
      uint4 st;
      st.x = h2u(h[4*cc+0]);
      st.y = h2u(h[4*cc+1]);
      st.z = h2u(h[4*cc+2]);
      st.w = h2u(h[4*cc+3]);
      *reinterpret_cast<uint4*>(BG + 4*cc) = st;
    }
  }
  __syncthreads();                       // (3)
  // ---- P4a: inverse high-digit DFT ---------------------------------------
  {
    const int rw = t >> 4, L = t & 15;
    __half2* BR = buf + rw*RPW;
    float2 d[16];
#pragma unroll
    for (int kk = 0; kk < 16; kk++) d[kk] = __half22float2(BR[L + 20*kk]);
    dft16(d, +1.0f);
#pragma unroll
    for (int H = 0; H < 16; H++){
      const float2 x = d[sw4(H)];
      BR[L + 20*H] = __floats2half2_rn(x.x, x.y);
    }
  }
  __syncthreads();                       // (4)
  // ---- store p0 (transposed chunk [p][c][km]) ----------------------------
  {
    uint4* O4 = reinterpret_cast<uint4*>(
        chunkbuf + (size_t)(gl*2 + 0)*65536 + (size_t)t*256 + m16);
    const int cs = SKP(t);
#pragma unroll
    for (int q4 = 0; q4 < 4; q4++){
      uint4 st;
      st.x = h2u(buf[(4*q4+0)*RPW + cs]);
      st.y = h2u(buf[(4*q4+1)*RPW + cs]);
      st.z = h2u(buf[(4*q4+2)*RPW + cs]);
      st.w = h2u(buf[(4*q4+3)*RPW + cs]);
      O4[q4] = st;
    }
  }
  __syncthreads();                       // (5) store reads -> P3b writes
  // ---- P3b: reload Z from Fh; product p1; inv-low; tw --------------------
  {
    uint4 a0 = Fh4[0*256 + t], a1 = Fh4[1*256 + t];
    uint4 a2 = Fh4[2*256 + t], a3 = Fh4[3*256 + t];
    const uint4* Bt1 = reinterpret_cast<const uint4*>(
        resp_t + (((size_t)(r*2 + 1)*16 + mq)*256 + t)*16);
    uint4 b0 = Bt1[0], b1 = Bt1[1], b2 = Bt1[2], b3 = Bt1[3];
    uint32_t zw[16], bw[16];
    zw[0]=a0.x; zw[1]=a0.y; zw[2]=a0.z; zw[3]=a0.w;
    zw[4]=a1.x; zw[5]=a1.y; zw[6]=a1.z; zw[7]=a1.w;
    zw[8]=a2.x; zw[9]=a2.y; zw[10]=a2.z; zw[11]=a2.w;
    zw[12]=a3.x; zw[13]=a3.y; zw[14]=a3.z; zw[15]=a3.w;
    bw[0]=b0.x; bw[1]=b0.y; bw[2]=b0.z; bw[3]=b0.w;
    bw[4]=b1.x; bw[5]=b1.y; bw[6]=b1.z; bw[7]=b1.w;
    bw[8]=b2.x; bw[9]=b2.y; bw[10]=b2.z; bw[11]=b2.w;
    bw[12]=b3.x; bw[13]=b3.y; bw[14]=b3.z; bw[15]=b3.w;
    float2 v[16];
#pragma unroll
    for (int pp = 0; pp < 16; pp++){
      const float2 z = __half22float2(u2h(zw[pp]));
      const float2 b = __half22float2(u2h(bw[pp]));
      v[pp] = make_float2((z.x*b.x - z.y*b.y)*SCALE64K,
                          (z.x*b.y + z.y*b.x)*SCALE64K);
    }
    dft16b(v, +1.0f);
    __half2 h[16];
#pragma unroll
    for (int n2 = 0; n2 < 16; n2++){
      float2 m = v[n2];
      const float2 w = twl[(n2*k1) & 255];
      const float x = m.x*w.x + m.y*w.y;
      m.y = -m.x*w.y + m.y*w.x;
      m.x = x;
      h[n2] = __floats2half2_rn(m.x, m.y);
    }
#pragma unroll
    for (int cc = 0; cc < 4; cc++){
      uint4 st;
      st.x = h2u(h[4*cc+0]);
      st.y = h2u(h[4*cc+1]);
      st.z = h2u(h[4*cc+2]);
      st.w = h2u(h[4*cc+3]);
      *reinterpret_cast<uint4*>(BG + 4*cc) = st;
    }
  }
  __syncthreads();                       // (6)
  // ---- P4b ----------------------------------------------------------------
  {
    const int rw = t >> 4, L = t & 15;
    __half2* BR = buf + rw*RPW;
    float2 d[16];
#pragma unroll
    for (int kk = 0; kk < 16; kk++) d[kk] = __half22float2(BR[L + 20*kk]);
    dft16(d, +1.0f);
#pragma unroll
    for (int H = 0; H < 16; H++){
      const float2 x = d[sw4(H)];
      BR[L + 20*H] = __floats2half2_rn(x.x, x.y);
    }
  }
  __syncthreads();                       // (7)
  // ---- store p1 ----------------------------------------------------------
  {
    uint4* O4 = reinterpret_cast<uint4*>(
        chunkbuf + (size_t)(gl*2 + 1)*65536 + (size_t)t*256 + m16);
    const int cs = SKP(t);
#pragma unroll
    for (int q4 = 0; q4 < 4; q4++){
      uint4 st;
      st.x = h2u(buf[(4*q4+0)*RPW + cs]);
      st.y = h2u(buf[(4*q4+1)*RPW + cs]);
      st.z = h2u(buf[(4*q4+2)*RPW + cs]);
      st.w = h2u(buf[(4*q4+3)*RPW + cs]);
      O4[q4] = st;
    }
  }
}

// -- inverse comb (radix-16^2 registers) + softmax mix + tanh + atomicAdd ---
__global__ __launch_bounds__(256, 4)
void k_invA_w(const __half2* __restrict__ chunkbuf, const int gbase,
              const float* __restrict__ w_sm, const float* __restrict__ gains,
              float* __restrict__ out0){
  const int wg = blockIdx.x;
  const int c8 = wg & 31;
  const int gl = wg >> 5;
  const int g = gbase + gl;
  const int r = g & 31, be = g >> 5;
  const int c0 = c8*8;
  const int t = threadIdx.x;
  __shared__ alignas(16) __half2 buf[16*RPW];
  __shared__ float sm_lds[512];
  sm_lds[t]       = w_sm[be*512 + t];
  sm_lds[256 + t] = w_sm[be*512 + 256 + t];

  const int row = t >> 4;          // p*8 + cc
  const int p   = row >> 3;
  const int cc  = row & 7;
  const int c   = c0 + cc;
  // ---- P1: inverse 16-DFT over rhoH, bitrev-aware coalesced reads --------
  {
    const int u = t & 15;            // rhoL
    const uint4* C4 = reinterpret_cast<const uint4*>(
        chunkbuf + (size_t)(gl*2 + p)*65536 + (size_t)c*256 + 16*br4(u));
    uint4 z0 = C4[0], z1 = C4[1], z2 = C4[2], z3 = C4[3];
    uint32_t zw[16];
    zw[0]=z0.x; zw[1]=z0.y; zw[2]=z0.z; zw[3]=z0.w;
    zw[4]=z1.x; zw[5]=z1.y; zw[6]=z1.z; zw[7]=z1.w;
    zw[8]=z2.x; zw[9]=z2.y; zw[10]=z2.z; zw[11]=z2.w;
    zw[12]=z3.x; zw[13]=z3.y; zw[14]=z3.z; zw[15]=z3.w;
    const float2 wstep = twid((uint32_t)(16*c) & 0xFFFFu, UNIT64K, +1.0f);
    float2 w = make_float2(1.0f, 0.0f);
    float2 d[16];
#pragma unroll
    for (int rh = 0; rh < 16; rh++){
      d[rh] = cmul(__half22float2(u2h(zw[br4(rh)])), w);
      w = cmul(w, wstep);
    }
    dft16(d, +1.0f);                  // S[mL] at d[sw4(mL)]
    __half2* BR = buf + row*RPW;
#pragma unroll
    for (int mL = 0; mL < 16; mL++){
      const float2 s = d[sw4(mL)];
      BR[20*mL + u] = __floats2half2_rn(s.x, s.y);
    }
  }
  __syncthreads();
  // ---- P2: read consecutive, pre-twiddle, inverse 16-DFT over rhoL -------
  const int mL = t & 15;
  float2 v[16];
  {
    const __half2* BG = buf + row*RPW + 20*mL;
#pragma unroll
    for (int q4 = 0; q4 < 4; q4++){
      const uint4 ld = *reinterpret_cast<const uint4*>(BG + 4*q4);
      v[4*q4+0] = __half22float2(u2h(ld.x));
      v[4*q4+1] = __half22float2(u2h(ld.y));
      v[4*q4+2] = __half22float2(u2h(ld.z));
      v[4*q4+3] = __half22float2(u2h(ld.w));
    }
  }
  __syncthreads();                    // all P2 reads done before re-writes
  {
    const float2 wstep = twid((uint32_t)(c + 256*mL) & 0xFFFFu, UNIT64K, +1.0f);
    float2 w = wstep;
#pragma unroll
    for (int kL2 = 1; kL2 < 16; kL2++){
      v[kL2] = cmul(v[kL2], w);
      w = cmul(w, wstep);
    }
    dft16(v, +1.0f);                  // x[mL+16mH] at v[sw4(mH)]
    __half2* BR = buf + row*RPW;
#pragma unroll
    for (int mH = 0; mH < 8; mH++){   // keep m<128 only
      const float2 x = v[sw4(mH)];
      BR[mL + 20*mH] = __floats2half2_rn(x.x, x.y);
    }
  }
  __syncthreads();
  // ---- epilogue: softmax mix + tanh + atomicAdd --------------------------
  const float gv = fabsf(gains[r]);
#pragma unroll
  for (int it = 0; it < 4; it++){
    const int li = t + it*256;        // li = m*8 + cc2, m < 128
    const int cc2 = li & 7, m = li >> 3;
    const int tt = c0 + cc2 + 256*m;
    int lo, hi; float w;
    interp128(tt, lo, hi, w);
    const int cell = (m & 15) + 20*(m >> 4);   // SKP(m)
    float2 z0 = __half22float2(buf[cc2*RPW + cell]);
    float2 z1 = __half22float2(buf[(8 + cc2)*RPW + cell]);
    float dw0 = sm_lds[0*128 + lo]*(1.0f - w) + sm_lds[0*128 + hi]*w;
    float dw1 = sm_lds[1*128 + lo]*(1.0f - w) + sm_lds[1*128 + hi]*w;
    float dw2 = sm_lds[2*128 + lo]*(1.0f - w) + sm_lds[2*128 + hi]*w;
    float dw3 = sm_lds[3*128 + lo]*(1.0f - w) + sm_lds[3*128 + hi]*w;
    float val = dw0*z0.x + dw1*z0.y + dw2*z1.x + dw3*z1.y;  // scale pre-folded
    atomicAdd(&out0[(size_t)be*32768 + tt], tanhf(val*gv));
  }
}

extern "C" void kernel_launch(void* const* d_in, const int* in_sizes, int n_in,
                              void* d_out, int out_size, void* d_ws, size_t ws_size,
                              hipStream_t stream){
  const float* ctrl   = (const float*)d_in[0];
  const float* defm   = (const float*)d_in[1];
  const float* router = (const float*)d_in[2];
  const float* amp    = (const float*)d_in[3];
  const float* phase  = (const float*)d_in[4];
  const float* decay  = (const float*)d_in[5];
  const float* gains  = (const float*)d_in[6];
  float* out = (float*)d_out;
  float* ws  = (float*)d_ws;

  // ws layout (float offsets)
  float*   w_resT    = ws;                          // 4,194,304 (dead after
                                                    // fwdA m0 -> reused as resp_t)
  float*   w_routed  = ws + 4194304;                // 32,768
  float*   w_sm      = ws + 4227072;                // 4,096
  float*   w_invnorm = ws + 4231168;                // 128
  float*   w_sumsq   = ws + 4231296;                // 128
  __half2* ruspec_h  = (__half2*)(ws + 4231424);    // 256*65536 h2 = 16,777,216 f
  __half2* resp_h    = (__half2*)(ws + 21008640);   // 64*65536 h2  =  4,194,304 f
  __half2* chunk_h   = (__half2*)(ws + 25202944);   // 2G*65536 h2  = G*131,072 f
  const size_t base_f = 25202944;
  // frames scratch aliases ruspec_h region (ruspec written later by fwdA)
  float2* w_fr       = (float2*)ruspec_h;           // 2048*2048 c = 8,388,608 f
  // resp_t (k_conv-order res spectra) reuses w_resT: 64*65536 h2 = 16MB exact
  __half2* resp_t    = (__half2*)w_resT;
  // pql (k_prep output) aliases resp_h: consumed before fwdA m0 writes it
  float4*  pql       = (float4*)resp_h;

  int G = 0;
  for (int gg = 256; gg >= 1; gg >>= 1){
    size_t need = (base_f + (size_t)gg*131072) * sizeof(float);
    if (need <= ws_size){ G = gg; break; }
  }

  hipMemsetAsync(d_out, 0, 262144*sizeof(float), stream);  // out0 (atomicAdd)
  k_routed<<<132, 256, 0, stream>>>(ctrl, defm, router, w_routed, w_sm, out + 262144);
  if (G == 0) return;  // diagnostic: out1 ok, out0 stays 0 => ws too small

  hipMemsetAsync(w_sumsq, 0, 128*sizeof(float), stream);
  k_prep<<<513, 256, 0, stream>>>(amp, phase, decay, pql);
  k_frames<<<2048, 256, 0, stream>>>(pql, w_fr);
  k_ola<<<512, 256, 0, stream>>>(w_fr, w_resT, w_sumsq);
  k_norm<<<1, 128, 0, stream>>>(w_sumsq, w_invnorm);
  k_fwdA<<<64*16, 256, 0, stream>>>(0, w_resT, w_invnorm, w_routed, resp_h);
  k_fwdB<<<64*16, 256, 0, stream>>>(resp_h, resp_t);
  k_fwdA<<<256*16, 256, 0, stream>>>(1, w_resT, w_invnorm, w_routed, ruspec_h);
  for (int gb = 0; gb < 256; gb += G){
    const int remap = (G == 256) ? 1 : 0;
    k_conv<<<G*16, 256, 0, stream>>>(ruspec_h, resp_t, chunk_h, gb, remap);
    k_invA_w<<<G*32, 256, 0, stream>>>(chunk_h, gb, w_sm, gains, out);
  }
}

// Round 15
// 304.652 us; speedup vs baseline: 1.0090x; 1.0090x over previous
//
#include <hip/hip_runtime.h>
#include <hip/hip_fp16.h>
#include <stdint.h>

// ResonanceLayer: routed einsum -> resonance irfft (x-pair packed, frames to
// scratch) -> OLA+transpose+norm -> upsample*threefry-noise -> 65536-pt FFT
// convolution with complex-packed res spectra -> softmax-deformation mix ->
// tanh(gain*x) summed over resonators.
//
// Round-27: packed-half P4 in k_conv. r26's conflict fix (8.3e6->5.1e6) was
// time-neutral -> conflicts off the critical path; kernel is VALU/issue
// bound (60% VALU, 35% HBM). P4a/P4b are pure h2->DFT->h2 passes that paid
// 32 h2<->f32 cvts + 164 f32 ops each; new dft16h_inv does the whole pass
// in packed-half (__hadd2/__hsub2 complex add, swap+signed-mul for *i,
// 3-op pk_fma cmuls) ~= 107 ops, no cvts. ~13% VALU cut on k_conv.
// Accuracy: post-scale values O(1-10), 4 add-levels of h16 rounding ~2e-3
// rel -> absmax expected ~0.07-0.12 (threshold 0.24). Rest = r26.

#define PI_F     3.14159265358979323846f
#define TWOPI_F  6.28318530717958647692f
#define UNIT64K  (TWOPI_F/65536.0f)
#define UNIT2K   (TWOPI_F/2048.0f)
#define SCALE64K (1.0f/65536.0f)
#define SKP(i)   ((i) + 4*((i) >> 4))    // block-FFT pad: 16B-aligned groups
#define RPW 340                          // block-FFT row pitch (=20 mod 32)

__device__ __forceinline__ float2 cmul(float2 a, float2 b){
  return make_float2(a.x*b.x - a.y*b.y, a.x*b.y + a.y*b.x);
}

__device__ __forceinline__ float2 twid(uint32_t e, float unit, float sign){
  float ang = (float)e * unit;
  float sn, cn;
  __sincosf(ang, &sn, &cn);
  return make_float2(cn, sign*sn);
}

__device__ __forceinline__ uint32_t rotl32(uint32_t v, int r){
  return (v << r) | (v >> (32 - r));
}

// Threefry-2x32, key = (0, 123)
__device__ __forceinline__ void threefry2x32(uint32_t c0, uint32_t c1,
                                             uint32_t& o0, uint32_t& o1){
  const uint32_t k0 = 0u, k1 = 123u;
  const uint32_t k2 = 0x1BD11BDAu ^ k0 ^ k1;
  const uint32_t ks[3] = {k0, k1, k2};
  uint32_t x0 = c0 + k0, x1 = c1 + k1;
#pragma unroll
  for (int i = 0; i < 5; i++){
    if ((i & 1) == 0){
      x0 += x1; x1 = rotl32(x1,13); x1 ^= x0;
      x0 += x1; x1 = rotl32(x1,15); x1 ^= x0;
      x0 += x1; x1 = rotl32(x1,26); x1 ^= x0;
      x0 += x1; x1 = rotl32(x1, 6); x1 ^= x0;
    } else {
      x0 += x1; x1 = rotl32(x1,17); x1 ^= x0;
      x0 += x1; x1 = rotl32(x1,29); x1 ^= x0;
      x0 += x1; x1 = rotl32(x1,16); x1 ^= x0;
      x0 += x1; x1 = rotl32(x1,24); x1 ^= x0;
    }
    x0 += ks[(i+1)%3];
    x1 += ks[(i+2)%3] + (uint32_t)(i+1);
  }
  o0 = x0; o1 = x1;
}

__device__ __forceinline__ float jax_noise(uint32_t p){
  uint32_t b0, b1;
  threefry2x32(0u, p, b0, b1);
  uint32_t bits = b0 ^ b1;
  float u = __uint_as_float((bits >> 9) | 0x3f800000u) - 1.0f;
  return fmaxf(-1.0f, u*2.0f - 1.0f);
}

__device__ __forceinline__ void interp128(int t, int& lo, int& hi, float& w){
  float posf = ((float)t + 0.5f) * (1.0f/256.0f) - 0.5f;
  posf = fminf(fmaxf(posf, 0.0f), 127.0f);
  lo = (int)posf;
  hi = lo + 1; if (hi > 127) hi = 127;
  w = posf - (float)lo;
}

// ------------------------- radix-16 register FFT ---------------------------
__device__ __forceinline__ __half2 u2h(uint32_t u){
  union { uint32_t u; __half2 h; } x; x.u = u; return x.h;
}
__device__ __forceinline__ uint32_t h2u(__half2 h){
  union { uint32_t u; __half2 h; } x; x.h = h; return x.u;
}
__device__ __forceinline__ constexpr int sw4(int k){ return ((k & 3) << 2) | (k >> 2); }
__device__ __forceinline__ constexpr int br4(int x){
  return ((x & 1) << 3) | ((x & 2) << 1) | ((x & 4) >> 1) | ((x & 8) >> 3);
}

// u *= (c + i s)
__device__ __forceinline__ void cws(float2& u, const float c, const float s){
  const float x = u.x*c - u.y*s;
  u.y = u.x*s + u.y*c;
  u.x = x;
}
__device__ __forceinline__ void cwv(float2& u, const float2 w){
  const float x = u.x*w.x - u.y*w.y;
  u.y = u.x*w.y + u.y*w.x;
  u.x = x;
}

// radix-4 butterfly, sgn = -1 fwd (e^{-i}), +1 inv (e^{+i})
__device__ __forceinline__ void dft4(float2& a, float2& b, float2& c, float2& d,
                                     const float sgn){
  float2 t0 = make_float2(a.x + c.x, a.y + c.y);
  float2 t1 = make_float2(a.x - c.x, a.y - c.y);
  float2 t2 = make_float2(b.x + d.x, b.y + d.y);
  float2 t3 = make_float2(b.x - d.x, b.y - d.y);
  float2 i3 = make_float2(-sgn*t3.y, sgn*t3.x);   // sgn*i*t3
  a = make_float2(t0.x + t2.x, t0.y + t2.y);      // y0
  c = make_float2(t0.x - t2.x, t0.y - t2.y);      // y2
  b = make_float2(t1.x + i3.x, t1.y + i3.y);      // y1
  d = make_float2(t1.x - i3.x, t1.y - i3.y);      // y3
}

// W16 twiddles at positions p: j(p) = (p>>2)*(p&3) — identical for dft16/dft16b
#define DFT16_TW(d, sgn) do { \
  const float C1_ = 0.92387953251128674f, S1_ = 0.38268343236508978f; \
  const float C2_ = 0.70710678118654752f; \
  cws(d[5],  C1_,  (sgn)*S1_); \
  cws(d[6],  C2_,  (sgn)*C2_); \
  cws(d[7],  S1_,  (sgn)*C1_); \
  cws(d[9],  C2_,  (sgn)*C2_); \
  cws(d[10], 0.0f, (sgn)); \
  cws(d[11], -C2_, (sgn)*C2_); \
  cws(d[13], S1_,  (sgn)*C1_); \
  cws(d[14], -C2_, (sgn)*C2_); \
  cws(d[15], -C1_, -(sgn)*S1_); \
} while(0)

// 16-pt DFT: input x[n] at d[n] natural; output X[k] at d[sw4(k)]
__device__ __forceinline__ void dft16(float2* d, const float sgn){
#pragma unroll
  for (int nb = 0; nb < 4; nb++) dft4(d[nb], d[nb+4], d[nb+8], d[nb+12], sgn);
  DFT16_TW(d, sgn);
#pragma unroll
  for (int ka = 0; ka < 4; ka++) dft4(d[4*ka], d[4*ka+1], d[4*ka+2], d[4*ka+3], sgn);
}
// 16-pt DFT, swapped-input variant: input x[n] at d[sw4(n)]; output X[k] at d[k]
__device__ __forceinline__ void dft16b(float2* d, const float sgn){
#pragma unroll
  for (int nb = 0; nb < 4; nb++) dft4(d[4*nb], d[4*nb+1], d[4*nb+2], d[4*nb+3], sgn);
  DFT16_TW(d, sgn);
#pragma unroll
  for (int ka = 0; ka < 4; ka++) dft4(d[ka], d[ka+4], d[ka+8], d[ka+12], sgn);
}

// ---------------- packed-half inverse 16-pt DFT (sgn = +1) -----------------
#define H2C(a,b) __halves2half2(__float2half(a), __float2half(b))
// radix-4 butterfly in packed half; IC = (-1,+1) implements *(+i)
__device__ __forceinline__ void dft4h(__half2& a, __half2& b, __half2& c,
                                      __half2& d, const __half2 IC){
  __half2 t0 = __hadd2(a, c), t1 = __hsub2(a, c);
  __half2 t2 = __hadd2(b, d), t3 = __hsub2(b, d);
  __half2 i3 = __hmul2(__lowhigh2highlow(t3), IC);
  a = __hadd2(t0, t2); c = __hsub2(t0, t2);
  b = __hadd2(t1, i3); d = __hsub2(t1, i3);
}
// z *= (cw + i sw): fma(swap(z), (-sw,sw), z*(cw,cw))
__device__ __forceinline__ __half2 cwh(__half2 z, const float cw, const float sw){
  return __hfma2(__lowhigh2highlow(z), H2C(-sw, sw),
                 __hmul2(z, __float2half2_rn(cw)));
}
// input x[n] at d[n] natural; output X[k] at d[sw4(k)]
__device__ __forceinline__ void dft16h_inv(__half2* d){
  const __half2 IC = H2C(-1.0f, 1.0f);          // *(+i)
  const float C1 = 0.92387953251128674f, S1 = 0.38268343236508978f;
  const float C2 = 0.70710678118654752f;
#pragma unroll
  for (int nb = 0; nb < 4; nb++) dft4h(d[nb], d[nb+4], d[nb+8], d[nb+12], IC);
  d[5]  = cwh(d[5],  C1,  S1);
  d[6]  = cwh(d[6],  C2,  C2);
  d[7]  = cwh(d[7],  S1,  C1);
  d[9]  = cwh(d[9],  C2,  C2);
  d[10] = __hmul2(__lowhigh2highlow(d[10]), IC);  // *(0,+1) = +i
  d[11] = cwh(d[11], -C2, C2);
  d[13] = cwh(d[13], S1,  C1);
  d[14] = cwh(d[14], -C2, C2);
  d[15] = cwh(d[15], -C1, -S1);
#pragma unroll
  for (int ka = 0; ka < 4; ka++) dft4h(d[4*ka], d[4*ka+1], d[4*ka+2], d[4*ka+3], IC);
}

// P1 fwd: per (row, L): 16-DFT over high digit H (strided cells L+20H),
// twiddle W_256^{L*k1}, write slot(L+16k1) = cell L+20k1.
__device__ __forceinline__ void pass1_fwd(__half2* buf, const float2* twl, const int t){
  const int row = t >> 4, L = t & 15;
  __half2* BR = buf + row*RPW;
  float2 d[16];
#pragma unroll
  for (int H = 0; H < 16; H++) d[H] = __half22float2(BR[L + 20*H]);
  dft16(d, -1.0f);
#pragma unroll
  for (int k1 = 0; k1 < 16; k1++){
    float2 y = d[sw4(k1)];
    cwv(y, twl[(L*k1) & 255]);
    BR[L + 20*k1] = __floats2half2_rn(y.x, y.y);
  }
}

// ---------------- routed einsum + output1 + softmax(deformations) ----------
__global__ void k_routed(const float* __restrict__ ctrl, const float* __restrict__ defm,
                         const float* __restrict__ router,
                         float* __restrict__ w_routed, float* __restrict__ w_sm,
                         float* __restrict__ out1){
  int idx = blockIdx.x*blockDim.x + threadIdx.x;
  if (idx < 32768){
    int f = idx & 127, r = (idx >> 7) & 31, be = idx >> 12;
    float acc = 0.0f;
#pragma unroll
    for (int c = 0; c < 16; c++)
      acc += ctrl[(be*16 + c)*128 + f] * router[c*32 + r];
    w_routed[idx] = acc;
    out1[idx] = acc;
  } else if (idx < 32768 + 1024){
    int j = idx - 32768;
    int f = j & 127, be = j >> 7;
    float v[4];
#pragma unroll
    for (int x = 0; x < 4; x++)
      v[x] = defm[(be*4 + x)*128 + f] + (x == 0 ? 1.0f : 0.0f);
    float mx = fmaxf(fmaxf(v[0], v[1]), fmaxf(v[2], v[3]));
    float s = 0.0f;
#pragma unroll
    for (int x = 0; x < 4; x++){ v[x] = expf(v[x] - mx); s += v[x]; }
#pragma unroll
    for (int x = 0; x < 4; x++) w_sm[(be*4 + x)*128 + f] = v[x]/s;
  }
}

// ---- param precompute: per (r,k,x): (a cos, a sin, log_dc) ----------------
__global__ void k_prep(const float* __restrict__ amp, const float* __restrict__ phase,
                       const float* __restrict__ decay, float4* __restrict__ pql){
  const int idx = blockIdx.x*256 + threadIdx.x;
  if (idx >= 131200) return;           // 32 r * 1025 k * 4 x
  float a  = fabsf(amp[idx]);
  float ph = tanhf(phase[idx]) * PI_F;
  float sg = 1.0f / (1.0f + expf(-decay[idx]));
  float dc = 0.5f + 0.45f * sg;
  float L  = logf(dc + 1e-12f);
  float sn, cs;
  sincosf(ph, &sn, &cs);
  pql[idx] = make_float4(a*cs, a*sn, L, 0.0f);
}

// ---- resonance frames: packed complex irfft(2048) of x-pairs + hann -------
__global__ void k_frames(const float4* __restrict__ pql, float2* __restrict__ w_fr){
  const int wg = blockIdx.x;          // (r,p,f)
  const int f = wg & 31;
  const int rp = wg >> 5;             // r*2 + p
  const int p = rp & 1;
  const int r = rp >> 1;
  const int t = threadIdx.x;
  __shared__ float2 buf[2048];
  __shared__ float2 twl2[1024];

  for (int i = t; i < 1024; i += 256)
    twl2[i] = twid((uint32_t)i, UNIT2K, +1.0f);

  const float fp1 = (float)(f + 1);
  for (int k = t; k <= 1024; k += 256){
    float2 S[2];
#pragma unroll
    for (int d = 0; d < 2; d++){
      const int x = 2*p + d;
      const float4 q = pql[(r*1025 + k)*4 + x];
      const float e = __expf(q.z * fp1);
      float re = e*q.x, im = e*q.y;
      if (k == 0 || k == 1024) im = 0.0f;
      S[d] = make_float2(re, im);
    }
    buf[__brev((uint32_t)k) >> 21] =
        make_float2(S[0].x - S[1].y, S[0].y + S[1].x);
    if (k >= 1 && k <= 1023)
      buf[__brev((uint32_t)(2048 - k)) >> 21] =
          make_float2(S[0].x + S[1].y, -S[0].y + S[1].x);
  }
  __syncthreads();
  for (int s = 10; s >= 0; s--){
    const int ls = 10 - s;
    const int hl = 1 << ls;
    for (int bi = t; bi < 1024; bi += 256){
      const int g = bi >> ls, j = bi & (hl - 1);
      const int i0 = g*2*hl + j, i1 = i0 + hl;
      float2 pp = buf[i0], qq = buf[i1];
      float2 w = twl2[j << s];
      float2 v = cmul(qq, w);
      buf[i0] = make_float2(pp.x+v.x, pp.y+v.y);
      buf[i1] = make_float2(pp.x-v.x, pp.y-v.y);
    }
    __syncthreads();
  }
  float2* O = w_fr + (size_t)wg*2048;
  for (int u = t; u < 2048; u += 256){
    float hann = 0.5f - 0.5f*cosf(TWOPI_F * (float)u / 2048.0f);
    float sc = (1.0f/2048.0f) * hann;
    O[u] = make_float2(buf[u].x*sc, buf[u].y*sc);
  }
}

// ---- OLA + transpose + sum-of-squares ------------------------------------
__global__ void k_ola(const float2* __restrict__ w_fr, float* __restrict__ w_resT,
                      float* __restrict__ w_sumsq){
  const int wg = blockIdx.x;           // rp*8 + cq
  const int cq = wg & 7;
  const int rp = wg >> 3;
  const int c0 = cq*32;
  const int r = rp >> 1, p = rp & 1;
  const int ch0 = r*4 + p*2;
  const int t = threadIdx.x;
  __shared__ float tx[32][129], ty[32][129];
  __shared__ float red[2][256];
  const float2* F = w_fr + (size_t)rp*32*2048;
  float acc0 = 0.0f, acc1 = 0.0f;
#pragma unroll
  for (int it = 0; it < 16; it++){
    const int idx = it*256 + t;        // m*32 + c'  (time-ordered reads)
    const int cp = idx & 31, m = idx >> 5;
    const int n = c0 + cp + 256*m;
    const int f = n >> 10, u = n & 1023;
    float2 a = F[(size_t)f*2048 + u];
    float vx = a.x, vy = a.y;
    if (f > 0){
      float2 b = F[(size_t)(f-1)*2048 + u + 1024];
      vx += b.x; vy += b.y;
    }
    tx[cp][m] = vx; ty[cp][m] = vy;
    acc0 += vx*vx; acc1 += vy*vy;
  }
  red[0][t] = acc0; red[1][t] = acc1;
  __syncthreads();
#pragma unroll
  for (int it = 0; it < 16; it++){
    const int idx = it*256 + t;        // c'*128 + m  (contiguous writes)
    const int m = idx & 127, cp = idx >> 7;
    w_resT[(size_t)ch0*32768 + (size_t)(c0+cp)*128 + m]     = tx[cp][m];
    w_resT[(size_t)(ch0+1)*32768 + (size_t)(c0+cp)*128 + m] = ty[cp][m];
  }
  for (int off = 128; off > 0; off >>= 1){
    __syncthreads();
    if (t < off){ red[0][t] += red[0][t+off]; red[1][t] += red[1][t+off]; }
  }
  if (t == 0){
    atomicAdd(&w_sumsq[ch0],     red[0][0]);
    atomicAdd(&w_sumsq[ch0 + 1], red[1][0]);
  }
}

// ---------------- invnorm from sumsq (1 tiny block) ------------------------
__global__ void k_norm(const float* __restrict__ w_sumsq, float* __restrict__ w_invnorm){
  const int s = threadIdx.x;
  if (s < 128) w_invnorm[s] = 1.0f/(sqrtf(w_sumsq[s]) + 1e-8f);
}

// --------- forward comb (radix-16^2 registers), mirror of k_invA_w ---------
__global__ __launch_bounds__(256, 4)
void k_fwdA(const int mode, const float* __restrict__ w_resT,
            const float* __restrict__ w_invnorm,
            const float* __restrict__ w_routed,
            __half2* __restrict__ outh){
  const int wg = blockIdx.x;
  const int cq = wg & 15;
  const int sig = wg >> 4;
  const int t = threadIdx.x;
  const int cc = t >> 4;
  const int c  = cq*16 + cc;
  __shared__ alignas(16) __half2 buf[16*RPW];

  // ---- P1: inputs direct to regs, dft16(-1) over mH, chained twiddle -----
  {
    const int mL = t & 15;
    float2 d[16];
    if (mode == 0){
      const int rr = sig >> 1, pq = sig & 1;
      const int ch0 = rr*4 + pq*2;
      const float inv0 = w_invnorm[ch0], inv1 = w_invnorm[ch0+1];
      const float* X0 = w_resT + (size_t)ch0*32768 + (size_t)c*128;
      const float* X1 = w_resT + (size_t)(ch0+1)*32768 + (size_t)c*128;
#pragma unroll
      for (int mH = 0; mH < 8; mH++){
        const int m = mL + 16*mH;
        d[mH] = make_float2(X0[m]*inv0, X1[m]*inv1);
      }
#pragma unroll
      for (int mH = 8; mH < 16; mH++) d[mH] = make_float2(0.0f, 0.0f);
    } else {
      const float* rp = w_routed + sig*128;
#pragma unroll
      for (int mH = 0; mH < 8; mH++){
        const int m = mL + 16*mH;
        const int n = c + 256*m;
        int lo, hi; float w;
        interp128(n, lo, hi, w);
        float rv = rp[lo]*(1.0f - w) + rp[hi]*w;
        d[mH] = make_float2(rv * jax_noise((uint32_t)sig*32768u + (uint32_t)n), 0.0f);
      }
#pragma unroll
      for (int mH = 8; mH < 16; mH++) d[mH] = make_float2(0.0f, 0.0f);
    }
    dft16(d, -1.0f);                   // T[rhoL] at d[sw4(rhoL)]
    const float2 wstep = twid((uint32_t)(c + 256*mL) & 0xFFFFu, UNIT64K, -1.0f);
    float2 w = wstep;
    __half2* BR = buf + cc*RPW;
    BR[mL] = __floats2half2_rn(d[0].x, d[0].y);       // rhoL=0 (w^0)
#pragma unroll
    for (int rl = 1; rl < 16; rl++){
      float2 y = d[sw4(rl)];
      cwv(y, w);
      w = cmul(w, wstep);
      BR[20*rl + mL] = __floats2half2_rn(y.x, y.y);
    }
  }
  __syncthreads();
  // ---- P2: consecutive reads, dft16(-1) over mL, post-twiddle, store -----
  {
    const int rl = t & 15;             // rhoL
    const __half2* BG = buf + cc*RPW + 20*rl;
    float2 v[16];
#pragma unroll
    for (int q4 = 0; q4 < 4; q4++){
      const uint4 ld = *reinterpret_cast<const uint4*>(BG + 4*q4);
      v[4*q4+0] = __half22float2(u2h(ld.x));
      v[4*q4+1] = __half22float2(u2h(ld.y));
      v[4*q4+2] = __half22float2(u2h(ld.z));
      v[4*q4+3] = __half22float2(u2h(ld.w));
    }
    dft16(v, -1.0f);                   // U[rhoH] at v[sw4(rhoH)]
    const float2 wstep = twid((uint32_t)(16*c) & 0xFFFFu, UNIT64K, -1.0f);
    float2 w = wstep;
    __half2 y[16];
    y[0] = __floats2half2_rn(v[0].x, v[0].y);         // rhoH=0 (sw4(0)=0)
#pragma unroll
    for (int rh = 1; rh < 16; rh++){
      float2 u = v[sw4(rh)];
      cwv(u, w);
      w = cmul(w, wstep);
      y[rh] = __floats2half2_rn(u.x, u.y);
    }
    // store at positions j in group 16*br4(rl): value y[br4(j)]
    uint4* O4 = reinterpret_cast<uint4*>(
        outh + (size_t)sig*65536 + (size_t)c*256 + 16*br4(rl));
#pragma unroll
    for (int q4 = 0; q4 < 4; q4++){
      uint4 st;
      st.x = h2u(y[br4(4*q4+0)]);
      st.y = h2u(y[br4(4*q4+1)]);
      st.z = h2u(y[br4(4*q4+2)]);
      st.w = h2u(y[br4(4*q4+3)]);
      O4[q4] = st;
    }
  }
}

// ------- forward block stages (radix-16^2) for res spectra -----------------
__global__ __launch_bounds__(256, 4)
void k_fwdB(const __half2* __restrict__ spech, __half2* __restrict__ resp_t){
  const int wg = blockIdx.x;
  const int mq = wg & 15;
  const int sig = wg >> 4;
  const int m16 = mq*16;
  const int t = threadIdx.x;
  __shared__ alignas(16) __half2 buf[16*RPW];
  __shared__ float2 twl[256];
  twl[t] = twid((uint32_t)t << 8, UNIT64K, -1.0f);
  const __half2* base = spech + (size_t)sig*65536;
  {
    const int mm = t & 15, q = t >> 4;
    __half2* BR = buf + mm*RPW;
#pragma unroll
    for (int i = 0; i < 16; i++)
      BR[20*i + q] = base[(size_t)(16*i + q)*256 + m16 + mm];
  }
  __syncthreads();
  pass1_fwd(buf, twl, t);
  __syncthreads();
  {
    const int k1 = t >> 4, row = t & 15;
    __half2* BG = buf + row*RPW + 20*k1;
    float2 v[16];
#pragma unroll
    for (int cc = 0; cc < 4; cc++){
      const uint4 ld = *reinterpret_cast<const uint4*>(BG + 4*cc);
      v[4*cc+0] = __half22float2(u2h(ld.x));
      v[4*cc+1] = __half22float2(u2h(ld.y));
      v[4*cc+2] = __half22float2(u2h(ld.z));
      v[4*cc+3] = __half22float2(u2h(ld.w));
    }
    dft16(v, -1.0f);
    uint4* O4 = reinterpret_cast<uint4*>(resp_t + (((size_t)sig*16 + mq)*256 + t)*16);
#pragma unroll
    for (int cc = 0; cc < 4; cc++){
      uint4 st;
      st.x = h2u(__floats2half2_rn(v[4*cc+0].x, v[4*cc+0].y));
      st.y = h2u(__floats2half2_rn(v[4*cc+1].x, v[4*cc+1].y));
      st.z = h2u(__floats2half2_rn(v[4*cc+2].x, v[4*cc+2].y));
      st.w = h2u(__floats2half2_rn(v[4*cc+3].x, v[4*cc+3].y));
      O4[cc] = st;
    }
  }
}

// ---- FUSED: ru fwd (radix-16^2) + BOTH products + inverses, 1 blk/(g,mq) --
// Forward spectrum Z parked in LDS Fh, quad-interleaved (Fh4[cc*256+t]).
// remap=1 (G=256): slice-major XCD-affine block order for resp_t L2 reuse.
// P4a/P4b in packed-half (dft16h_inv).
__global__ __launch_bounds__(256, 4)
void k_conv(const __half2* __restrict__ ruspec,
            const __half2* __restrict__ resp_t,
            __half2* __restrict__ chunkbuf, const int gbase, const int remap){
  const int wg = blockIdx.x;
  int mq, gl;
  if (remap){
    // id = sOuter*64 + be*8 + xcd ; s = sOuter*8 + xcd = mq*32 + r
    const int xcd = wg & 7, be = (wg >> 3) & 7, sOuter = wg >> 6;
    const int s = sOuter*8 + xcd;
    mq = s >> 5;
    const int r8 = s & 31;
    gl = be*32 + r8;                   // gbase = 0 in this mode
  } else {
    mq = wg & 15;
    gl = wg >> 4;
  }
  const int g = gbase + gl;
  const int r = g & 31;
  const int m16 = mq*16;
  const int t = threadIdx.x;
  __shared__ alignas(16) __half2 buf[16*RPW];
  __shared__ alignas(16) __half2 Fh[4096];
  __shared__ float2 twl[256];
  twl[t] = twid((uint32_t)t << 8, UNIT64K, -1.0f);
  uint4* Fh4 = reinterpret_cast<uint4*>(Fh);

  // staging (once): thread t owns slot c = t; 4x uint4 contiguous
  {
    const uint4* A4 = reinterpret_cast<const uint4*>(
        ruspec + (size_t)g*65536 + (size_t)t*256 + m16);
    uint4 a0 = A4[0], a1 = A4[1], a2 = A4[2], a3 = A4[3];
    const int cs = SKP(t);
    uint32_t w[16];
    w[0]=a0.x; w[1]=a0.y; w[2]=a0.z; w[3]=a0.w;
    w[4]=a1.x; w[5]=a1.y; w[6]=a1.z; w[7]=a1.w;
    w[8]=a2.x; w[9]=a2.y; w[10]=a2.z; w[11]=a2.w;
    w[12]=a3.x; w[13]=a3.y; w[14]=a3.z; w[15]=a3.w;
#pragma unroll
    for (int mm = 0; mm < 16; mm++)
      buf[mm*RPW + cs] = u2h(w[mm]);
  }
  __syncthreads();                       // (1)
  pass1_fwd(buf, twl, t);
  __syncthreads();                       // (2)
  const int k1 = t >> 4, row = t & 15;
  __half2* BG = buf + row*RPW + 20*k1;
  // ---- P3a: fwd dft16 once; snapshot Z->Fh; product p0; inv-low; tw ------
  {
    float2 v[16];
#pragma unroll
    for (int cc = 0; cc < 4; cc++){
      const uint4 ld = *reinterpret_cast<const uint4*>(BG + 4*cc);
      v[4*cc+0] = __half22float2(u2h(ld.x));
      v[4*cc+1] = __half22float2(u2h(ld.y));
      v[4*cc+2] = __half22float2(u2h(ld.z));
      v[4*cc+3] = __half22float2(u2h(ld.w));
    }
    const uint4* Bt0 = reinterpret_cast<const uint4*>(
        resp_t + (((size_t)(r*2 + 0)*16 + mq)*256 + t)*16);
    uint4 b0 = Bt0[0], b1 = Bt0[1], b2 = Bt0[2], b3 = Bt0[3];
    dft16(v, -1.0f);                    // Z[k2] at v[sw4(k2)]
    // park Z in Fh, quad-interleaved: start bank 4t mod 32 (uniform)
#pragma unroll
    for (int cc = 0; cc < 4; cc++){
      uint4 st;
      st.x = h2u(__floats2half2_rn(v[4*cc+0].x, v[4*cc+0].y));
      st.y = h2u(__floats2half2_rn(v[4*cc+1].x, v[4*cc+1].y));
      st.z = h2u(__floats2half2_rn(v[4*cc+2].x, v[4*cc+2].y));
      st.w = h2u(__floats2half2_rn(v[4*cc+3].x, v[4*cc+3].y));
      Fh4[cc*256 + t] = st;
    }
    uint32_t bw[16];
    bw[0]=b0.x; bw[1]=b0.y; bw[2]=b0.z; bw[3]=b0.w;
    bw[4]=b1.x; bw[5]=b1.y; bw[6]=b1.z; bw[7]=b1.w;
    bw[8]=b2.x; bw[9]=b2.y; bw[10]=b2.z; bw[11]=b2.w;
    bw[12]=b3.x; bw[13]=b3.y; bw[14]=b3.z; bw[15]=b3.w;
#pragma unroll
    for (int pp = 0; pp < 16; pp++){
      const float2 b = __half22float2(u2h(bw[pp]));
      const float zx = v[pp].x, zy = v[pp].y;
      v[pp] = make_float2((zx*b.x - zy*b.y)*SCALE64K,
                          (zx*b.y + zy*b.x)*SCALE64K);
    }
    dft16b(v, +1.0f);                   // m[n2] at v[n2]
    __half2 h[16];
#pragma unroll
    for (int n2 = 0; n2 < 16; n2++){    // conj twiddle W_256^{-n2*k1}
      float2 m = v[n2];
      const float2 w = twl[(n2*k1) & 255];
      const float x = m.x*w.x + m.y*w.y;
      m.y = -m.x*w.y + m.y*w.x;
      m.x = x;
      h[n2] = __floats2half2_rn(m.x, m.y);
    }
#pragma unroll
    for (int cc = 0; cc < 4; cc++){
      uint4 st;
      st.x = h2u(h[4*cc+0]);
      st.y = h2u(h[4*cc+1]);
      st.z = h2u(h[4*cc+2]);
      st.w = h2u(h[4*cc+3]);
      *reinterpret_cast<uint4*>(BG + 4*cc) = st;
    }
  }
  __syncthreads();                       // (3)
  // ---- P4a: inverse high-digit DFT (packed half) -------------------------
  {
    const int rw = t >> 4, L = t & 15;
    __half2* BR = buf + rw*RPW;
    __half2 dh[16];
#pragma unroll
    for (int kk = 0; kk < 16; kk++) dh[kk] = BR[L + 20*kk];
    dft16h_inv(dh);
#pragma unroll
    for (int H = 0; H < 16; H++) BR[L + 20*H] = dh[sw4(H)];
  }
  __syncthreads();                       // (4)
  // ---- store p0 (transposed chunk [p][c][km]) ----------------------------
  {
    uint4* O4 = reinterpret_cast<uint4*>(
        chunkbuf + (size_t)(gl*2 + 0)*65536 + (size_t)t*256 + m16);
    const int cs = SKP(t);
#pragma unroll
    for (int q4 = 0; q4 < 4; q4++){
      uint4 st;
      st.x = h2u(buf[(4*q4+0)*RPW + cs]);
      st.y = h2u(buf[(4*q4+1)*RPW + cs]);
      st.z = h2u(buf[(4*q4+2)*RPW + cs]);
      st.w = h2u(buf[(4*q4+3)*RPW + cs]);
      O4[q4] = st;
    }
  }
  __syncthreads();                       // (5) store reads -> P3b writes
  // ---- P3b: reload Z from Fh; product p1; inv-low; tw --------------------
  {
    uint4 a0 = Fh4[0*256 + t], a1 = Fh4[1*256 + t];
    uint4 a2 = Fh4[2*256 + t], a3 = Fh4[3*256 + t];
    const uint4* Bt1 = reinterpret_cast<const uint4*>(
        resp_t + (((size_t)(r*2 + 1)*16 + mq)*256 + t)*16);
    uint4 b0 = Bt1[0], b1 = Bt1[1], b2 = Bt1[2], b3 = Bt1[3];
    uint32_t zw[16], bw[16];
    zw[0]=a0.x; zw[1]=a0.y; zw[2]=a0.z; zw[3]=a0.w;
    zw[4]=a1.x; zw[5]=a1.y; zw[6]=a1.z; zw[7]=a1.w;
    zw[8]=a2.x; zw[9]=a2.y; zw[10]=a2.z; zw[11]=a2.w;
    zw[12]=a3.x; zw[13]=a3.y; zw[14]=a3.z; zw[15]=a3.w;
    bw[0]=b0.x; bw[1]=b0.y; bw[2]=b0.z; bw[3]=b0.w;
    bw[4]=b1.x; bw[5]=b1.y; bw[6]=b1.z; bw[7]=b1.w;
    bw[8]=b2.x; bw[9]=b2.y; bw[10]=b2.z; bw[11]=b2.w;
    bw[12]=b3.x; bw[13]=b3.y; bw[14]=b3.z; bw[15]=b3.w;
    float2 v[16];
#pragma unroll
    for (int pp = 0; pp < 16; pp++){
      const float2 z = __half22float2(u2h(zw[pp]));
      const float2 b = __half22float2(u2h(bw[pp]));
      v[pp] = make_float2((z.x*b.x - z.y*b.y)*SCALE64K,
                          (z.x*b.y + z.y*b.x)*SCALE64K);
    }
    dft16b(v, +1.0f);
    __half2 h[16];
#pragma unroll
    for (int n2 = 0; n2 < 16; n2++){
      float2 m = v[n2];
      const float2 w = twl[(n2*k1) & 255];
      const float x = m.x*w.x + m.y*w.y;
      m.y = -m.x*w.y + m.y*w.x;
      m.x = x;
      h[n2] = __floats2half2_rn(m.x, m.y);
    }
#pragma unroll
    for (int cc = 0; cc < 4; cc++){
      uint4 st;
      st.x = h2u(h[4*cc+0]);
      st.y = h2u(h[4*cc+1]);
      st.z = h2u(h[4*cc+2]);
      st.w = h2u(h[4*cc+3]);
      *reinterpret_cast<uint4*>(BG + 4*cc) = st;
    }
  }
  __syncthreads();                       // (6)
  // ---- P4b (packed half) --------------------------------------------------
  {
    const int rw = t >> 4, L = t & 15;
    __half2* BR = buf + rw*RPW;
    __half2 dh[16];
#pragma unroll
    for (int kk = 0; kk < 16; kk++) dh[kk] = BR[L + 20*kk];
    dft16h_inv(dh);
#pragma unroll
    for (int H = 0; H < 16; H++) BR[L + 20*H] = dh[sw4(H)];
  }
  __syncthreads();                       // (7)
  // ---- store p1 ----------------------------------------------------------
  {
    uint4* O4 = reinterpret_cast<uint4*>(
        chunkbuf + (size_t)(gl*2 + 1)*65536 + (size_t)t*256 + m16);
    const int cs = SKP(t);
#pragma unroll
    for (int q4 = 0; q4 < 4; q4++){
      uint4 st;
      st.x = h2u(buf[(4*q4+0)*RPW + cs]);
      st.y = h2u(buf[(4*q4+1)*RPW + cs]);
      st.z = h2u(buf[(4*q4+2)*RPW + cs]);
      st.w = h2u(buf[(4*q4+3)*RPW + cs]);
      O4[q4] = st;
    }
  }
}

// -- inverse comb (radix-16^2 registers) + softmax mix + tanh + atomicAdd ---
__global__ __launch_bounds__(256, 4)
void k_invA_w(const __half2* __restrict__ chunkbuf, const int gbase,
              const float* __restrict__ w_sm, const float* __restrict__ gains,
              float* __restrict__ out0){
  const int wg = blockIdx.x;
  const int c8 = wg & 31;
  const int gl = wg >> 5;
  const int g = gbase + gl;
  const int r = g & 31, be = g >> 5;
  const int c0 = c8*8;
  const int t = threadIdx.x;
  __shared__ alignas(16) __half2 buf[16*RPW];
  __shared__ float sm_lds[512];
  sm_lds[t]       = w_sm[be*512 + t];
  sm_lds[256 + t] = w_sm[be*512 + 256 + t];

  const int row = t >> 4;          // p*8 + cc
  const int p   = row >> 3;
  const int cc  = row & 7;
  const int c   = c0 + cc;
  // ---- P1: inverse 16-DFT over rhoH, bitrev-aware coalesced reads --------
  {
    const int u = t & 15;            // rhoL
    const uint4* C4 = reinterpret_cast<const uint4*>(
        chunkbuf + (size_t)(gl*2 + p)*65536 + (size_t)c*256 + 16*br4(u));
    uint4 z0 = C4[0], z1 = C4[1], z2 = C4[2], z3 = C4[3];
    uint32_t zw[16];
    zw[0]=z0.x; zw[1]=z0.y; zw[2]=z0.z; zw[3]=z0.w;
    zw[4]=z1.x; zw[5]=z1.y; zw[6]=z1.z; zw[7]=z1.w;
    zw[8]=z2.x; zw[9]=z2.y; zw[10]=z2.z; zw[11]=z2.w;
    zw[12]=z3.x; zw[13]=z3.y; zw[14]=z3.z; zw[15]=z3.w;
    const float2 wstep = twid((uint32_t)(16*c) & 0xFFFFu, UNIT64K, +1.0f);
    float2 w = make_float2(1.0f, 0.0f);
    float2 d[16];
#pragma unroll
    for (int rh = 0; rh < 16; rh++){
      d[rh] = cmul(__half22float2(u2h(zw[br4(rh)])), w);
      w = cmul(w, wstep);
    }
    dft16(d, +1.0f);                  // S[mL] at d[sw4(mL)]
    __half2* BR = buf + row*RPW;
#pragma unroll
    for (int mL = 0; mL < 16; mL++){
      const float2 s = d[sw4(mL)];
      BR[20*mL + u] = __floats2half2_rn(s.x, s.y);
    }
  }
  __syncthreads();
  // ---- P2: read consecutive, pre-twiddle, inverse 16-DFT over rhoL -------
  const int mL = t & 15;
  float2 v[16];
  {
    const __half2* BG = buf + row*RPW + 20*mL;
#pragma unroll
    for (int q4 = 0; q4 < 4; q4++){
      const uint4 ld = *reinterpret_cast<const uint4*>(BG + 4*q4);
      v[4*q4+0] = __half22float2(u2h(ld.x));
      v[4*q4+1] = __half22float2(u2h(ld.y));
      v[4*q4+2] = __half22float2(u2h(ld.z));
      v[4*q4+3] = __half22float2(u2h(ld.w));
    }
  }
  __syncthreads();                    // all P2 reads done before re-writes
  {
    const float2 wstep = twid((uint32_t)(c + 256*mL) & 0xFFFFu, UNIT64K, +1.0f);
    float2 w = wstep;
#pragma unroll
    for (int kL2 = 1; kL2 < 16; kL2++){
      v[kL2] = cmul(v[kL2], w);
      w = cmul(w, wstep);
    }
    dft16(v, +1.0f);                  // x[mL+16mH] at v[sw4(mH)]
    __half2* BR = buf + row*RPW;
#pragma unroll
    for (int mH = 0; mH < 8; mH++){   // keep m<128 only
      const float2 x = v[sw4(mH)];
      BR[mL + 20*mH] = __floats2half2_rn(x.x, x.y);
    }
  }
  __syncthreads();
  // ---- epilogue: softmax mix + tanh + atomicAdd --------------------------
  const float gv = fabsf(gains[r]);
#pragma unroll
  for (int it = 0; it < 4; it++){
    const int li = t + it*256;        // li = m*8 + cc2, m < 128
    const int cc2 = li & 7, m = li >> 3;
    const int tt = c0 + cc2 + 256*m;
    int lo, hi; float w;
    interp128(tt, lo, hi, w);
    const int cell = (m & 15) + 20*(m >> 4);   // SKP(m)
    float2 z0 = __half22float2(buf[cc2*RPW + cell]);
    float2 z1 = __half22float2(buf[(8 + cc2)*RPW + cell]);
    float dw0 = sm_lds[0*128 + lo]*(1.0f - w) + sm_lds[0*128 + hi]*w;
    float dw1 = sm_lds[1*128 + lo]*(1.0f - w) + sm_lds[1*128 + hi]*w;
    float dw2 = sm_lds[2*128 + lo]*(1.0f - w) + sm_lds[2*128 + hi]*w;
    float dw3 = sm_lds[3*128 + lo]*(1.0f - w) + sm_lds[3*128 + hi]*w;
    float val = dw0*z0.x + dw1*z0.y + dw2*z1.x + dw3*z1.y;  // scale pre-folded
    atomicAdd(&out0[(size_t)be*32768 + tt], tanhf(val*gv));
  }
}

extern "C" void kernel_launch(void* const* d_in, const int* in_sizes, int n_in,
                              void* d_out, int out_size, void* d_ws, size_t ws_size,
                              hipStream_t stream){
  const float* ctrl   = (const float*)d_in[0];
  const float* defm   = (const float*)d_in[1];
  const float* router = (const float*)d_in[2];
  const float* amp    = (const float*)d_in[3];
  const float* phase  = (const float*)d_in[4];
  const float* decay  = (const float*)d_in[5];
  const float* gains  = (const float*)d_in[6];
  float* out = (float*)d_out;
  float* ws  = (float*)d_ws;

  // ws layout (float offsets)
  float*   w_resT    = ws;                          // 4,194,304 (dead after
                                                    // fwdA m0 -> reused as resp_t)
  float*   w_routed  = ws + 4194304;                // 32,768
  float*   w_sm      = ws + 4227072;                // 4,096
  float*   w_invnorm = ws + 4231168;                // 128
  float*   w_sumsq   = ws + 4231296;                // 128
  __half2* ruspec_h  = (__half2*)(ws + 4231424);    // 256*65536 h2 = 16,777,216 f
  __half2* resp_h    = (__half2*)(ws + 21008640);   // 64*65536 h2  =  4,194,304 f
  __half2* chunk_h   = (__half2*)(ws + 25202944);   // 2G*65536 h2  = G*131,072 f
  const size_t base_f = 25202944;
  // frames scratch aliases ruspec_h region (ruspec written later by fwdA)
  float2* w_fr       = (float2*)ruspec_h;           // 2048*2048 c = 8,388,608 f
  // resp_t (k_conv-order res spectra) reuses w_resT: 64*65536 h2 = 16MB exact
  __half2* resp_t    = (__half2*)w_resT;
  // pql (k_prep output) aliases resp_h: consumed before fwdA m0 writes it
  float4*  pql       = (float4*)resp_h;

  int G = 0;
  for (int gg = 256; gg >= 1; gg >>= 1){
    size_t need = (base_f + (size_t)gg*131072) * sizeof(float);
    if (need <= ws_size){ G = gg; break; }
  }

  hipMemsetAsync(d_out, 0, 262144*sizeof(float), stream);  // out0 (atomicAdd)
  k_routed<<<132, 256, 0, stream>>>(ctrl, defm, router, w_routed, w_sm, out + 262144);
  if (G == 0) return;  // diagnostic: out1 ok, out0 stays 0 => ws too small

  hipMemsetAsync(w_sumsq, 0, 128*sizeof(float), stream);
  k_prep<<<513, 256, 0, stream>>>(amp, phase, decay, pql);
  k_frames<<<2048, 256, 0, stream>>>(pql, w_fr);
  k_ola<<<512, 256, 0, stream>>>(w_fr, w_resT, w_sumsq);
  k_norm<<<1, 128, 0, stream>>>(w_sumsq, w_invnorm);
  k_fwdA<<<64*16, 256, 0, stream>>>(0, w_resT, w_invnorm, w_routed, resp_h);
  k_fwdB<<<64*16, 256, 0, stream>>>(resp_h, resp_t);
  k_fwdA<<<256*16, 256, 0, stream>>>(1, w_resT, w_invnorm, w_routed, ruspec_h);
  for (int gb = 0; gb < 256; gb += G){
    const int remap = (G == 256) ? 1 : 0;
    k_conv<<<G*16, 256, 0, stream>>>(ruspec_h, resp_t, chunk_h, gb, remap);
    k_invA_w<<<G*32, 256, 0, stream>>>(chunk_h, gb, w_sm, gains, out);
  }
}

// Round 16
// 299.759 us; speedup vs baseline: 1.0255x; 1.0163x over previous
//
#include <hip/hip_runtime.h>
#include <hip/hip_fp16.h>
#include <stdint.h>

// ResonanceLayer: routed einsum -> resonance irfft (x-pair packed, frames to
// scratch) -> OLA+transpose+norm -> upsample*threefry-noise -> 65536-pt FFT
// convolution with complex-packed res spectra -> softmax-deformation mix ->
// tanh(gain*x) summed over resonators.
//
// Round-28: extend packed-half to ALL inverse-side DFT passes (r27 proved
// h16 error sits below the bf16 output floor: absmax stayed 0.0625).
//  * k_conv P3a/P3b: product (f32, scale folded) -> h2 once ->
//    dft16bh_inv (packed-half, swapped-input) -> conj twiddle via table read
//    + cwh. ~90 fewer ops/thread per P3.
//  * k_invA_w P2: post-twiddle v -> h2 -> dft16h_inv -> store.
// Forward-side DFTs stay f32 (large spectrum magnitudes + chained twiddles).
// Rest identical to r27 (304.7us, k_conv 73.7us).

#define PI_F     3.14159265358979323846f
#define TWOPI_F  6.28318530717958647692f
#define UNIT64K  (TWOPI_F/65536.0f)
#define UNIT2K   (TWOPI_F/2048.0f)
#define SCALE64K (1.0f/65536.0f)
#define SKP(i)   ((i) + 4*((i) >> 4))    // block-FFT pad: 16B-aligned groups
#define RPW 340                          // block-FFT row pitch (=20 mod 32)

__device__ __forceinline__ float2 cmul(float2 a, float2 b){
  return make_float2(a.x*b.x - a.y*b.y, a.x*b.y + a.y*b.x);
}

__device__ __forceinline__ float2 twid(uint32_t e, float unit, float sign){
  float ang = (float)e * unit;
  float sn, cn;
  __sincosf(ang, &sn, &cn);
  return make_float2(cn, sign*sn);
}

__device__ __forceinline__ uint32_t rotl32(uint32_t v, int r){
  return (v << r) | (v >> (32 - r));
}

// Threefry-2x32, key = (0, 123)
__device__ __forceinline__ void threefry2x32(uint32_t c0, uint32_t c1,
                                             uint32_t& o0, uint32_t& o1){
  const uint32_t k0 = 0u, k1 = 123u;
  const uint32_t k2 = 0x1BD11BDAu ^ k0 ^ k1;
  const uint32_t ks[3] = {k0, k1, k2};
  uint32_t x0 = c0 + k0, x1 = c1 + k1;
#pragma unroll
  for (int i = 0; i < 5; i++){
    if ((i & 1) == 0){
      x0 += x1; x1 = rotl32(x1,13); x1 ^= x0;
      x0 += x1; x1 = rotl32(x1,15); x1 ^= x0;
      x0 += x1; x1 = rotl32(x1,26); x1 ^= x0;
      x0 += x1; x1 = rotl32(x1, 6); x1 ^= x0;
    } else {
      x0 += x1; x1 = rotl32(x1,17); x1 ^= x0;
      x0 += x1; x1 = rotl32(x1,29); x1 ^= x0;
      x0 += x1; x1 = rotl32(x1,16); x1 ^= x0;
      x0 += x1; x1 = rotl32(x1,24); x1 ^= x0;
    }
    x0 += ks[(i+1)%3];
    x1 += ks[(i+2)%3] + (uint32_t)(i+1);
  }
  o0 = x0; o1 = x1;
}

__device__ __forceinline__ float jax_noise(uint32_t p){
  uint32_t b0, b1;
  threefry2x32(0u, p, b0, b1);
  uint32_t bits = b0 ^ b1;
  float u = __uint_as_float((bits >> 9) | 0x3f800000u) - 1.0f;
  return fmaxf(-1.0f, u*2.0f - 1.0f);
}

__device__ __forceinline__ void interp128(int t, int& lo, int& hi, float& w){
  float posf = ((float)t + 0.5f) * (1.0f/256.0f) - 0.5f;
  posf = fminf(fmaxf(posf, 0.0f), 127.0f);
  lo = (int)posf;
  hi = lo + 1; if (hi > 127) hi = 127;
  w = posf - (float)lo;
}

// ------------------------- radix-16 register FFT ---------------------------
__device__ __forceinline__ __half2 u2h(uint32_t u){
  union { uint32_t u; __half2 h; } x; x.u = u; return x.h;
}
__device__ __forceinline__ uint32_t h2u(__half2 h){
  union { uint32_t u; __half2 h; } x; x.h = h; return x.u;
}
__device__ __forceinline__ constexpr int sw4(int k){ return ((k & 3) << 2) | (k >> 2); }
__device__ __forceinline__ constexpr int br4(int x){
  return ((x & 1) << 3) | ((x & 2) << 1) | ((x & 4) >> 1) | ((x & 8) >> 3);
}

// u *= (c + i s)
__device__ __forceinline__ void cws(float2& u, const float c, const float s){
  const float x = u.x*c - u.y*s;
  u.y = u.x*s + u.y*c;
  u.x = x;
}
__device__ __forceinline__ void cwv(float2& u, const float2 w){
  const float x = u.x*w.x - u.y*w.y;
  u.y = u.x*w.y + u.y*w.x;
  u.x = x;
}

// radix-4 butterfly, sgn = -1 fwd (e^{-i}), +1 inv (e^{+i})
__device__ __forceinline__ void dft4(float2& a, float2& b, float2& c, float2& d,
                                     const float sgn){
  float2 t0 = make_float2(a.x + c.x, a.y + c.y);
  float2 t1 = make_float2(a.x - c.x, a.y - c.y);
  float2 t2 = make_float2(b.x + d.x, b.y + d.y);
  float2 t3 = make_float2(b.x - d.x, b.y - d.y);
  float2 i3 = make_float2(-sgn*t3.y, sgn*t3.x);   // sgn*i*t3
  a = make_float2(t0.x + t2.x, t0.y + t2.y);      // y0
  c = make_float2(t0.x - t2.x, t0.y - t2.y);      // y2
  b = make_float2(t1.x + i3.x, t1.y + i3.y);      // y1
  d = make_float2(t1.x - i3.x, t1.y - i3.y);      // y3
}

// W16 twiddles at positions p: j(p) = (p>>2)*(p&3) — identical for dft16/dft16b
#define DFT16_TW(d, sgn) do { \
  const float C1_ = 0.92387953251128674f, S1_ = 0.38268343236508978f; \
  const float C2_ = 0.70710678118654752f; \
  cws(d[5],  C1_,  (sgn)*S1_); \
  cws(d[6],  C2_,  (sgn)*C2_); \
  cws(d[7],  S1_,  (sgn)*C1_); \
  cws(d[9],  C2_,  (sgn)*C2_); \
  cws(d[10], 0.0f, (sgn)); \
  cws(d[11], -C2_, (sgn)*C2_); \
  cws(d[13], S1_,  (sgn)*C1_); \
  cws(d[14], -C2_, (sgn)*C2_); \
  cws(d[15], -C1_, -(sgn)*S1_); \
} while(0)

// 16-pt DFT: input x[n] at d[n] natural; output X[k] at d[sw4(k)]
__device__ __forceinline__ void dft16(float2* d, const float sgn){
#pragma unroll
  for (int nb = 0; nb < 4; nb++) dft4(d[nb], d[nb+4], d[nb+8], d[nb+12], sgn);
  DFT16_TW(d, sgn);
#pragma unroll
  for (int ka = 0; ka < 4; ka++) dft4(d[4*ka], d[4*ka+1], d[4*ka+2], d[4*ka+3], sgn);
}

// ---------------- packed-half inverse 16-pt DFTs (sgn = +1) ----------------
#define H2C(a,b) __halves2half2(__float2half(a), __float2half(b))
// radix-4 butterfly in packed half; IC = (-1,+1) implements *(+i)
__device__ __forceinline__ void dft4h(__half2& a, __half2& b, __half2& c,
                                      __half2& d, const __half2 IC){
  __half2 t0 = __hadd2(a, c), t1 = __hsub2(a, c);
  __half2 t2 = __hadd2(b, d), t3 = __hsub2(b, d);
  __half2 i3 = __hmul2(__lowhigh2highlow(t3), IC);
  a = __hadd2(t0, t2); c = __hsub2(t0, t2);
  b = __hadd2(t1, i3); d = __hsub2(t1, i3);
}
// z *= (cw + i sw): fma(swap(z), (-sw,sw), z*(cw,cw))
__device__ __forceinline__ __half2 cwh(__half2 z, const float cw, const float sw){
  return __hfma2(__lowhigh2highlow(z), H2C(-sw, sw),
                 __hmul2(z, __float2half2_rn(cw)));
}
#define DFT16H_TW(d) do { \
  const float C1 = 0.92387953251128674f, S1 = 0.38268343236508978f; \
  const float C2 = 0.70710678118654752f; \
  d[5]  = cwh(d[5],  C1,  S1); \
  d[6]  = cwh(d[6],  C2,  C2); \
  d[7]  = cwh(d[7],  S1,  C1); \
  d[9]  = cwh(d[9],  C2,  C2); \
  d[10] = __hmul2(__lowhigh2highlow(d[10]), IC); \
  d[11] = cwh(d[11], -C2, C2); \
  d[13] = cwh(d[13], S1,  C1); \
  d[14] = cwh(d[14], -C2, C2); \
  d[15] = cwh(d[15], -C1, -S1); \
} while(0)
// input x[n] at d[n] natural; output X[k] at d[sw4(k)]
__device__ __forceinline__ void dft16h_inv(__half2* d){
  const __half2 IC = H2C(-1.0f, 1.0f);          // *(+i)
#pragma unroll
  for (int nb = 0; nb < 4; nb++) dft4h(d[nb], d[nb+4], d[nb+8], d[nb+12], IC);
  DFT16H_TW(d);
#pragma unroll
  for (int ka = 0; ka < 4; ka++) dft4h(d[4*ka], d[4*ka+1], d[4*ka+2], d[4*ka+3], IC);
}
// swapped-input variant: input x[n] at d[sw4(n)], output X[k] at d[k]
__device__ __forceinline__ void dft16bh_inv(__half2* d){
  const __half2 IC = H2C(-1.0f, 1.0f);          // *(+i)
#pragma unroll
  for (int nb = 0; nb < 4; nb++) dft4h(d[4*nb], d[4*nb+1], d[4*nb+2], d[4*nb+3], IC);
  DFT16H_TW(d);
#pragma unroll
  for (int ka = 0; ka < 4; ka++) dft4h(d[ka], d[ka+4], d[ka+8], d[ka+12], IC);
}

// P1 fwd: per (row, L): 16-DFT over high digit H (strided cells L+20H),
// twiddle W_256^{L*k1}, write slot(L+16k1) = cell L+20k1.
__device__ __forceinline__ void pass1_fwd(__half2* buf, const float2* twl, const int t){
  const int row = t >> 4, L = t & 15;
  __half2* BR = buf + row*RPW;
  float2 d[16];
#pragma unroll
  for (int H = 0; H < 16; H++) d[H] = __half22float2(BR[L + 20*H]);
  dft16(d, -1.0f);
#pragma unroll
  for (int k1 = 0; k1 < 16; k1++){
    float2 y = d[sw4(k1)];
    cwv(y, twl[(L*k1) & 255]);
    BR[L + 20*k1] = __floats2half2_rn(y.x, y.y);
  }
}

// ---------------- routed einsum + output1 + softmax(deformations) ----------
__global__ void k_routed(const float* __restrict__ ctrl, const float* __restrict__ defm,
                         const float* __restrict__ router,
                         float* __restrict__ w_routed, float* __restrict__ w_sm,
                         float* __restrict__ out1){
  int idx = blockIdx.x*blockDim.x + threadIdx.x;
  if (idx < 32768){
    int f = idx & 127, r = (idx >> 7) & 31, be = idx >> 12;
    float acc = 0.0f;
#pragma unroll
    for (int c = 0; c < 16; c++)
      acc += ctrl[(be*16 + c)*128 + f] * router[c*32 + r];
    w_routed[idx] = acc;
    out1[idx] = acc;
  } else if (idx < 32768 + 1024){
    int j = idx - 32768;
    int f = j & 127, be = j >> 7;
    float v[4];
#pragma unroll
    for (int x = 0; x < 4; x++)
      v[x] = defm[(be*4 + x)*128 + f] + (x == 0 ? 1.0f : 0.0f);
    float mx = fmaxf(fmaxf(v[0], v[1]), fmaxf(v[2], v[3]));
    float s = 0.0f;
#pragma unroll
    for (int x = 0; x < 4; x++){ v[x] = expf(v[x] - mx); s += v[x]; }
#pragma unroll
    for (int x = 0; x < 4; x++) w_sm[(be*4 + x)*128 + f] = v[x]/s;
  }
}

// ---- param precompute: per (r,k,x): (a cos, a sin, log_dc) ----------------
__global__ void k_prep(const float* __restrict__ amp, const float* __restrict__ phase,
                       const float* __restrict__ decay, float4* __restrict__ pql){
  const int idx = blockIdx.x*256 + threadIdx.x;
  if (idx >= 131200) return;           // 32 r * 1025 k * 4 x
  float a  = fabsf(amp[idx]);
  float ph = tanhf(phase[idx]) * PI_F;
  float sg = 1.0f / (1.0f + expf(-decay[idx]));
  float dc = 0.5f + 0.45f * sg;
  float L  = logf(dc + 1e-12f);
  float sn, cs;
  sincosf(ph, &sn, &cs);
  pql[idx] = make_float4(a*cs, a*sn, L, 0.0f);
}

// ---- resonance frames: packed complex irfft(2048) of x-pairs + hann -------
__global__ void k_frames(const float4* __restrict__ pql, float2* __restrict__ w_fr){
  const int wg = blockIdx.x;          // (r,p,f)
  const int f = wg & 31;
  const int rp = wg >> 5;             // r*2 + p
  const int p = rp & 1;
  const int r = rp >> 1;
  const int t = threadIdx.x;
  __shared__ float2 buf[2048];
  __shared__ float2 twl2[1024];

  for (int i = t; i < 1024; i += 256)
    twl2[i] = twid((uint32_t)i, UNIT2K, +1.0f);

  const float fp1 = (float)(f + 1);
  for (int k = t; k <= 1024; k += 256){
    float2 S[2];
#pragma unroll
    for (int d = 0; d < 2; d++){
      const int x = 2*p + d;
      const float4 q = pql[(r*1025 + k)*4 + x];
      const float e = __expf(q.z * fp1);
      float re = e*q.x, im = e*q.y;
      if (k == 0 || k == 1024) im = 0.0f;
      S[d] = make_float2(re, im);
    }
    buf[__brev((uint32_t)k) >> 21] =
        make_float2(S[0].x - S[1].y, S[0].y + S[1].x);
    if (k >= 1 && k <= 1023)
      buf[__brev((uint32_t)(2048 - k)) >> 21] =
          make_float2(S[0].x + S[1].y, -S[0].y + S[1].x);
  }
  __syncthreads();
  for (int s = 10; s >= 0; s--){
    const int ls = 10 - s;
    const int hl = 1 << ls;
    for (int bi = t; bi < 1024; bi += 256){
      const int g = bi >> ls, j = bi & (hl - 1);
      const int i0 = g*2*hl + j, i1 = i0 + hl;
      float2 pp = buf[i0], qq = buf[i1];
      float2 w = twl2[j << s];
      float2 v = cmul(qq, w);
      buf[i0] = make_float2(pp.x+v.x, pp.y+v.y);
      buf[i1] = make_float2(pp.x-v.x, pp.y-v.y);
    }
    __syncthreads();
  }
  float2* O = w_fr + (size_t)wg*2048;
  for (int u = t; u < 2048; u += 256){
    float hann = 0.5f - 0.5f*cosf(TWOPI_F * (float)u / 2048.0f);
    float sc = (1.0f/2048.0f) * hann;
    O[u] = make_float2(buf[u].x*sc, buf[u].y*sc);
  }
}

// ---- OLA + transpose + sum-of-squares ------------------------------------
__global__ void k_ola(const float2* __restrict__ w_fr, float* __restrict__ w_resT,
                      float* __restrict__ w_sumsq){
  const int wg = blockIdx.x;           // rp*8 + cq
  const int cq = wg & 7;
  const int rp = wg >> 3;
  const int c0 = cq*32;
  const int r = rp >> 1, p = rp & 1;
  const int ch0 = r*4 + p*2;
  const int t = threadIdx.x;
  __shared__ float tx[32][129], ty[32][129];
  __shared__ float red[2][256];
  const float2* F = w_fr + (size_t)rp*32*2048;
  float acc0 = 0.0f, acc1 = 0.0f;
#pragma unroll
  for (int it = 0; it < 16; it++){
    const int idx = it*256 + t;        // m*32 + c'  (time-ordered reads)
    const int cp = idx & 31, m = idx >> 5;
    const int n = c0 + cp + 256*m;
    const int f = n >> 10, u = n & 1023;
    float2 a = F[(size_t)f*2048 + u];
    float vx = a.x, vy = a.y;
    if (f > 0){
      float2 b = F[(size_t)(f-1)*2048 + u + 1024];
      vx += b.x; vy += b.y;
    }
    tx[cp][m] = vx; ty[cp][m] = vy;
    acc0 += vx*vx; acc1 += vy*vy;
  }
  red[0][t] = acc0; red[1][t] = acc1;
  __syncthreads();
#pragma unroll
  for (int it = 0; it < 16; it++){
    const int idx = it*256 + t;        // c'*128 + m  (contiguous writes)
    const int m = idx & 127, cp = idx >> 7;
    w_resT[(size_t)ch0*32768 + (size_t)(c0+cp)*128 + m]     = tx[cp][m];
    w_resT[(size_t)(ch0+1)*32768 + (size_t)(c0+cp)*128 + m] = ty[cp][m];
  }
  for (int off = 128; off > 0; off >>= 1){
    __syncthreads();
    if (t < off){ red[0][t] += red[0][t+off]; red[1][t] += red[1][t+off]; }
  }
  if (t == 0){
    atomicAdd(&w_sumsq[ch0],     red[0][0]);
    atomicAdd(&w_sumsq[ch0 + 1], red[1][0]);
  }
}

// ---------------- invnorm from sumsq (1 tiny block) ------------------------
__global__ void k_norm(const float* __restrict__ w_sumsq, float* __restrict__ w_invnorm){
  const int s = threadIdx.x;
  if (s < 128) w_invnorm[s] = 1.0f/(sqrtf(w_sumsq[s]) + 1e-8f);
}

// --------- forward comb (radix-16^2 registers), mirror of k_invA_w ---------
__global__ __launch_bounds__(256, 4)
void k_fwdA(const int mode, const float* __restrict__ w_resT,
            const float* __restrict__ w_invnorm,
            const float* __restrict__ w_routed,
            __half2* __restrict__ outh){
  const int wg = blockIdx.x;
  const int cq = wg & 15;
  const int sig = wg >> 4;
  const int t = threadIdx.x;
  const int cc = t >> 4;
  const int c  = cq*16 + cc;
  __shared__ alignas(16) __half2 buf[16*RPW];

  // ---- P1: inputs direct to regs, dft16(-1) over mH, chained twiddle -----
  {
    const int mL = t & 15;
    float2 d[16];
    if (mode == 0){
      const int rr = sig >> 1, pq = sig & 1;
      const int ch0 = rr*4 + pq*2;
      const float inv0 = w_invnorm[ch0], inv1 = w_invnorm[ch0+1];
      const float* X0 = w_resT + (size_t)ch0*32768 + (size_t)c*128;
      const float* X1 = w_resT + (size_t)(ch0+1)*32768 + (size_t)c*128;
#pragma unroll
      for (int mH = 0; mH < 8; mH++){
        const int m = mL + 16*mH;
        d[mH] = make_float2(X0[m]*inv0, X1[m]*inv1);
      }
#pragma unroll
      for (int mH = 8; mH < 16; mH++) d[mH] = make_float2(0.0f, 0.0f);
    } else {
      const float* rp = w_routed + sig*128;
#pragma unroll
      for (int mH = 0; mH < 8; mH++){
        const int m = mL + 16*mH;
        const int n = c + 256*m;
        int lo, hi; float w;
        interp128(n, lo, hi, w);
        float rv = rp[lo]*(1.0f - w) + rp[hi]*w;
        d[mH] = make_float2(rv * jax_noise((uint32_t)sig*32768u + (uint32_t)n), 0.0f);
      }
#pragma unroll
      for (int mH = 8; mH < 16; mH++) d[mH] = make_float2(0.0f, 0.0f);
    }
    dft16(d, -1.0f);                   // T[rhoL] at d[sw4(rhoL)]
    const float2 wstep = twid((uint32_t)(c + 256*mL) & 0xFFFFu, UNIT64K, -1.0f);
    float2 w = wstep;
    __half2* BR = buf + cc*RPW;
    BR[mL] = __floats2half2_rn(d[0].x, d[0].y);       // rhoL=0 (w^0)
#pragma unroll
    for (int rl = 1; rl < 16; rl++){
      float2 y = d[sw4(rl)];
      cwv(y, w);
      w = cmul(w, wstep);
      BR[20*rl + mL] = __floats2half2_rn(y.x, y.y);
    }
  }
  __syncthreads();
  // ---- P2: consecutive reads, dft16(-1) over mL, post-twiddle, store -----
  {
    const int rl = t & 15;             // rhoL
    const __half2* BG = buf + cc*RPW + 20*rl;
    float2 v[16];
#pragma unroll
    for (int q4 = 0; q4 < 4; q4++){
      const uint4 ld = *reinterpret_cast<const uint4*>(BG + 4*q4);
      v[4*q4+0] = __half22float2(u2h(ld.x));
      v[4*q4+1] = __half22float2(u2h(ld.y));
      v[4*q4+2] = __half22float2(u2h(ld.z));
      v[4*q4+3] = __half22float2(u2h(ld.w));
    }
    dft16(v, -1.0f);                   // U[rhoH] at v[sw4(rhoH)]
    const float2 wstep = twid((uint32_t)(16*c) & 0xFFFFu, UNIT64K, -1.0f);
    float2 w = wstep;
    __half2 y[16];
    y[0] = __floats2half2_rn(v[0].x, v[0].y);         // rhoH=0 (sw4(0)=0)
#pragma unroll
    for (int rh = 1; rh < 16; rh++){
      float2 u = v[sw4(rh)];
      cwv(u, w);
      w = cmul(w, wstep);
      y[rh] = __floats2half2_rn(u.x, u.y);
    }
    // store at positions j in group 16*br4(rl): value y[br4(j)]
    uint4* O4 = reinterpret_cast<uint4*>(
        outh + (size_t)sig*65536 + (size_t)c*256 + 16*br4(rl));
#pragma unroll
    for (int q4 = 0; q4 < 4; q4++){
      uint4 st;
      st.x = h2u(y[br4(4*q4+0)]);
      st.y = h2u(y[br4(4*q4+1)]);
      st.z = h2u(y[br4(4*q4+2)]);
      st.w = h2u(y[br4(4*q4+3)]);
      O4[q4] = st;
    }
  }
}

// ------- forward block stages (radix-16^2) for res spectra -----------------
__global__ __launch_bounds__(256, 4)
void k_fwdB(const __half2* __restrict__ spech, __half2* __restrict__ resp_t){
  const int wg = blockIdx.x;
  const int mq = wg & 15;
  const int sig = wg >> 4;
  const int m16 = mq*16;
  const int t = threadIdx.x;
  __shared__ alignas(16) __half2 buf[16*RPW];
  __shared__ float2 twl[256];
  twl[t] = twid((uint32_t)t << 8, UNIT64K, -1.0f);
  const __half2* base = spech + (size_t)sig*65536;
  {
    const int mm = t & 15, q = t >> 4;
    __half2* BR = buf + mm*RPW;
#pragma unroll
    for (int i = 0; i < 16; i++)
      BR[20*i + q] = base[(size_t)(16*i + q)*256 + m16 + mm];
  }
  __syncthreads();
  pass1_fwd(buf, twl, t);
  __syncthreads();
  {
    const int k1 = t >> 4, row = t & 15;
    __half2* BG = buf + row*RPW + 20*k1;
    float2 v[16];
#pragma unroll
    for (int cc = 0; cc < 4; cc++){
      const uint4 ld = *reinterpret_cast<const uint4*>(BG + 4*cc);
      v[4*cc+0] = __half22float2(u2h(ld.x));
      v[4*cc+1] = __half22float2(u2h(ld.y));
      v[4*cc+2] = __half22float2(u2h(ld.z));
      v[4*cc+3] = __half22float2(u2h(ld.w));
    }
    dft16(v, -1.0f);
    uint4* O4 = reinterpret_cast<uint4*>(resp_t + (((size_t)sig*16 + mq)*256 + t)*16);
#pragma unroll
    for (int cc = 0; cc < 4; cc++){
      uint4 st;
      st.x = h2u(__floats2half2_rn(v[4*cc+0].x, v[4*cc+0].y));
      st.y = h2u(__floats2half2_rn(v[4*cc+1].x, v[4*cc+1].y));
      st.z = h2u(__floats2half2_rn(v[4*cc+2].x, v[4*cc+2].y));
      st.w = h2u(__floats2half2_rn(v[4*cc+3].x, v[4*cc+3].y));
      O4[cc] = st;
    }
  }
}

// ---- FUSED: ru fwd (radix-16^2) + BOTH products + inverses, 1 blk/(g,mq) --
// Forward spectrum Z parked in LDS Fh, quad-interleaved (Fh4[cc*256+t]).
// remap=1 (G=256): slice-major XCD-affine block order for resp_t L2 reuse.
// P3a/P3b inverse-low + conj twiddle and P4a/P4b in packed-half.
__global__ __launch_bounds__(256, 4)
void k_conv(const __half2* __restrict__ ruspec,
            const __half2* __restrict__ resp_t,
            __half2* __restrict__ chunkbuf, const int gbase, const int remap){
  const int wg = blockIdx.x;
  int mq, gl;
  if (remap){
    // id = sOuter*64 + be*8 + xcd ; s = sOuter*8 + xcd = mq*32 + r
    const int xcd = wg & 7, be = (wg >> 3) & 7, sOuter = wg >> 6;
    const int s = sOuter*8 + xcd;
    mq = s >> 5;
    const int r8 = s & 31;
    gl = be*32 + r8;                   // gbase = 0 in this mode
  } else {
    mq = wg & 15;
    gl = wg >> 4;
  }
  const int g = gbase + gl;
  const int r = g & 31;
  const int m16 = mq*16;
  const int t = threadIdx.x;
  __shared__ alignas(16) __half2 buf[16*RPW];
  __shared__ alignas(16) __half2 Fh[4096];
  __shared__ float2 twl[256];
  twl[t] = twid((uint32_t)t << 8, UNIT64K, -1.0f);
  uint4* Fh4 = reinterpret_cast<uint4*>(Fh);

  // staging (once): thread t owns slot c = t; 4x uint4 contiguous
  {
    const uint4* A4 = reinterpret_cast<const uint4*>(
        ruspec + (size_t)g*65536 + (size_t)t*256 + m16);
    uint4 a0 = A4[0], a1 = A4[1], a2 = A4[2], a3 = A4[3];
    const int cs = SKP(t);
    uint32_t w[16];
    w[0]=a0.x; w[1]=a0.y; w[2]=a0.z; w[3]=a0.w;
    w[4]=a1.x; w[5]=a1.y; w[6]=a1.z; w[7]=a1.w;
    w[8]=a2.x; w[9]=a2.y; w[10]=a2.z; w[11]=a2.w;
    w[12]=a3.x; w[13]=a3.y; w[14]=a3.z; w[15]=a3.w;
#pragma unroll
    for (int mm = 0; mm < 16; mm++)
      buf[mm*RPW + cs] = u2h(w[mm]);
  }
  __syncthreads();                       // (1)
  pass1_fwd(buf, twl, t);
  __syncthreads();                       // (2)
  const int k1 = t >> 4, row = t & 15;
  __half2* BG = buf + row*RPW + 20*k1;
  // ---- P3a: fwd dft16 once; snapshot Z->Fh; product p0; half inv-low -----
  {
    float2 v[16];
#pragma unroll
    for (int cc = 0; cc < 4; cc++){
      const uint4 ld = *reinterpret_cast<const uint4*>(BG + 4*cc);
      v[4*cc+0] = __half22float2(u2h(ld.x));
      v[4*cc+1] = __half22float2(u2h(ld.y));
      v[4*cc+2] = __half22float2(u2h(ld.z));
      v[4*cc+3] = __half22float2(u2h(ld.w));
    }
    const uint4* Bt0 = reinterpret_cast<const uint4*>(
        resp_t + (((size_t)(r*2 + 0)*16 + mq)*256 + t)*16);
    uint4 b0 = Bt0[0], b1 = Bt0[1], b2 = Bt0[2], b3 = Bt0[3];
    dft16(v, -1.0f);                    // Z[k2] at v[sw4(k2)]
    // park Z in Fh, quad-interleaved: start bank 4t mod 32 (uniform)
#pragma unroll
    for (int cc = 0; cc < 4; cc++){
      uint4 st;
      st.x = h2u(__floats2half2_rn(v[4*cc+0].x, v[4*cc+0].y));
      st.y = h2u(__floats2half2_rn(v[4*cc+1].x, v[4*cc+1].y));
      st.z = h2u(__floats2half2_rn(v[4*cc+2].x, v[4*cc+2].y));
      st.w = h2u(__floats2half2_rn(v[4*cc+3].x, v[4*cc+3].y));
      Fh4[cc*256 + t] = st;
    }
    uint32_t bw[16];
    bw[0]=b0.x; bw[1]=b0.y; bw[2]=b0.z; bw[3]=b0.w;
    bw[4]=b1.x; bw[5]=b1.y; bw[6]=b1.z; bw[7]=b1.w;
    bw[8]=b2.x; bw[9]=b2.y; bw[10]=b2.z; bw[11]=b2.w;
    bw[12]=b3.x; bw[13]=b3.y; bw[14]=b3.z; bw[15]=b3.w;
    __half2 hv[16];
#pragma unroll
    for (int pp = 0; pp < 16; pp++){    // product in f32, then to h2
      const float2 b = __half22float2(u2h(bw[pp]));
      const float zx = v[pp].x, zy = v[pp].y;
      hv[pp] = __floats2half2_rn((zx*b.x - zy*b.y)*SCALE64K,
                                 (zx*b.y + zy*b.x)*SCALE64K);
    }
    dft16bh_inv(hv);                    // m[n2] at hv[n2] (packed half)
    __half2 h[16];
    h[0] = hv[0];
#pragma unroll
    for (int n2 = 1; n2 < 16; n2++){    // conj twiddle W_256^{-n2*k1}
      const float2 w = twl[(n2*k1) & 255];
      h[n2] = cwh(hv[n2], w.x, -w.y);
    }
#pragma unroll
    for (int cc = 0; cc < 4; cc++){
      uint4 st;
      st.x = h2u(h[4*cc+0]);
      st.y = h2u(h[4*cc+1]);
      st.z = h2u(h[4*cc+2]);
      st.w = h2u(h[4*cc+3]);
      *reinterpret_cast<uint4*>(BG + 4*cc) = st;
    }
  }
  __syncthreads();                       // (3)
  // ---- P4a: inverse high-digit DFT (packed half) -------------------------
  {
    const int rw = t >> 4, L = t & 15;
    __half2* BR = buf + rw*RPW;
    __half2 dh[16];
#pragma unroll
    for (int kk = 0; kk < 16; kk++) dh[kk] = BR[L + 20*kk];
    dft16h_inv(dh);
#pragma unroll
    for (int H = 0; H < 16; H++) BR[L + 20*H] = dh[sw4(H)];
  }
  __syncthreads();                       // (4)
  // ---- store p0 (transposed chunk [p][c][km]) ----------------------------
  {
    uint4* O4 = reinterpret_cast<uint4*>(
        chunkbuf + (size_t)(gl*2 + 0)*65536 + (size_t)t*256 + m16);
    const int cs = SKP(t);
#pragma unroll
    for (int q4 = 0; q4 < 4; q4++){
      uint4 st;
      st.x = h2u(buf[(4*q4+0)*RPW + cs]);
      st.y = h2u(buf[(4*q4+1)*RPW + cs]);
      st.z = h2u(buf[(4*q4+2)*RPW + cs]);
      st.w = h2u(buf[(4*q4+3)*RPW + cs]);
      O4[q4] = st;
    }
  }
  __syncthreads();                       // (5) store reads -> P3b writes
  // ---- P3b: reload Z from Fh; product p1; half inv-low -------------------
  {
    uint4 a0 = Fh4[0*256 + t], a1 = Fh4[1*256 + t];
    uint4 a2 = Fh4[2*256 + t], a3 = Fh4[3*256 + t];
    const uint4* Bt1 = reinterpret_cast<const uint4*>(
        resp_t + (((size_t)(r*2 + 1)*16 + mq)*256 + t)*16);
    uint4 b0 = Bt1[0], b1 = Bt1[1], b2 = Bt1[2], b3 = Bt1[3];
    uint32_t zw[16], bw[16];
    zw[0]=a0.x; zw[1]=a0.y; zw[2]=a0.z; zw[3]=a0.w;
    zw[4]=a1.x; zw[5]=a1.y; zw[6]=a1.z; zw[7]=a1.w;
    zw[8]=a2.x; zw[9]=a2.y; zw[10]=a2.z; zw[11]=a2.w;
    zw[12]=a3.x; zw[13]=a3.y; zw[14]=a3.z; zw[15]=a3.w;
    bw[0]=b0.x; bw[1]=b0.y; bw[2]=b0.z; bw[3]=b0.w;
    bw[4]=b1.x; bw[5]=b1.y; bw[6]=b1.z; bw[7]=b1.w;
    bw[8]=b2.x; bw[9]=b2.y; bw[10]=b2.z; bw[11]=b2.w;
    bw[12]=b3.x; bw[13]=b3.y; bw[14]=b3.z; bw[15]=b3.w;
    __half2 hv[16];
#pragma unroll
    for (int pp = 0; pp < 16; pp++){
      const float2 z = __half22float2(u2h(zw[pp]));
      const float2 b = __half22float2(u2h(bw[pp]));
      hv[pp] = __floats2half2_rn((z.x*b.x - z.y*b.y)*SCALE64K,
                                 (z.x*b.y + z.y*b.x)*SCALE64K);
    }
    dft16bh_inv(hv);
    __half2 h[16];
    h[0] = hv[0];
#pragma unroll
    for (int n2 = 1; n2 < 16; n2++){
      const float2 w = twl[(n2*k1) & 255];
      h[n2] = cwh(hv[n2], w.x, -w.y);
    }
#pragma unroll
    for (int cc = 0; cc < 4; cc++){
      uint4 st;
      st.x = h2u(h[4*cc+0]);
      st.y = h2u(h[4*cc+1]);
      st.z = h2u(h[4*cc+2]);
      st.w = h2u(h[4*cc+3]);
      *reinterpret_cast<uint4*>(BG + 4*cc) = st;
    }
  }
  __syncthreads();                       // (6)
  // ---- P4b (packed half) --------------------------------------------------
  {
    const int rw = t >> 4, L = t & 15;
    __half2* BR = buf + rw*RPW;
    __half2 dh[16];
#pragma unroll
    for (int kk = 0; kk < 16; kk++) dh[kk] = BR[L + 20*kk];
    dft16h_inv(dh);
#pragma unroll
    for (int H = 0; H < 16; H++) BR[L + 20*H] = dh[sw4(H)];
  }
  __syncthreads();                       // (7)
  // ---- store p1 ----------------------------------------------------------
  {
    uint4* O4 = reinterpret_cast<uint4*>(
        chunkbuf + (size_t)(gl*2 + 1)*65536 + (size_t)t*256 + m16);
    const int cs = SKP(t);
#pragma unroll
    for (int q4 = 0; q4 < 4; q4++){
      uint4 st;
      st.x = h2u(buf[(4*q4+0)*RPW + cs]);
      st.y = h2u(buf[(4*q4+1)*RPW + cs]);
      st.z = h2u(buf[(4*q4+2)*RPW + cs]);
      st.w = h2u(buf[(4*q4+3)*RPW + cs]);
      O4[q4] = st;
    }
  }
}

// -- inverse comb (radix-16^2 registers) + softmax mix + tanh + atomicAdd ---
// P2's final DFT in packed-half (post-twiddle values O(1), h2-stored anyway).
__global__ __launch_bounds__(256, 4)
void k_invA_w(const __half2* __restrict__ chunkbuf, const int gbase,
              const float* __restrict__ w_sm, const float* __restrict__ gains,
              float* __restrict__ out0){
  const int wg = blockIdx.x;
  const int c8 = wg & 31;
  const int gl = wg >> 5;
  const int g = gbase + gl;
  const int r = g & 31, be = g >> 5;
  const int c0 = c8*8;
  const int t = threadIdx.x;
  __shared__ alignas(16) __half2 buf[16*RPW];
  __shared__ float sm_lds[512];
  sm_lds[t]       = w_sm[be*512 + t];
  sm_lds[256 + t] = w_sm[be*512 + 256 + t];

  const int row = t >> 4;          // p*8 + cc
  const int p   = row >> 3;
  const int cc  = row & 7;
  const int c   = c0 + cc;
  // ---- P1: inverse 16-DFT over rhoH, bitrev-aware coalesced reads --------
  {
    const int u = t & 15;            // rhoL
    const uint4* C4 = reinterpret_cast<const uint4*>(
        chunkbuf + (size_t)(gl*2 + p)*65536 + (size_t)c*256 + 16*br4(u));
    uint4 z0 = C4[0], z1 = C4[1], z2 = C4[2], z3 = C4[3];
    uint32_t zw[16];
    zw[0]=z0.x; zw[1]=z0.y; zw[2]=z0.z; zw[3]=z0.w;
    zw[4]=z1.x; zw[5]=z1.y; zw[6]=z1.z; zw[7]=z1.w;
    zw[8]=z2.x; zw[9]=z2.y; zw[10]=z2.z; zw[11]=z2.w;
    zw[12]=z3.x; zw[13]=z3.y; zw[14]=z3.z; zw[15]=z3.w;
    const float2 wstep = twid((uint32_t)(16*c) & 0xFFFFu, UNIT64K, +1.0f);
    float2 w = make_float2(1.0f, 0.0f);
    float2 d[16];
#pragma unroll
    for (int rh = 0; rh < 16; rh++){
      d[rh] = cmul(__half22float2(u2h(zw[br4(rh)])), w);
      w = cmul(w, wstep);
    }
    dft16(d, +1.0f);                  // S[mL] at d[sw4(mL)]
    __half2* BR = buf + row*RPW;
#pragma unroll
    for (int mL = 0; mL < 16; mL++){
      const float2 s = d[sw4(mL)];
      BR[20*mL + u] = __floats2half2_rn(s.x, s.y);
    }
  }
  __syncthreads();
  // ---- P2: read consecutive, pre-twiddle, half inverse 16-DFT over rhoL --
  const int mL = t & 15;
  float2 v[16];
  {
    const __half2* BG = buf + row*RPW + 20*mL;
#pragma unroll
    for (int q4 = 0; q4 < 4; q4++){
      const uint4 ld = *reinterpret_cast<const uint4*>(BG + 4*q4);
      v[4*q4+0] = __half22float2(u2h(ld.x));
      v[4*q4+1] = __half22float2(u2h(ld.y));
      v[4*q4+2] = __half22float2(u2h(ld.z));
      v[4*q4+3] = __half22float2(u2h(ld.w));
    }
  }
  __syncthreads();                    // all P2 reads done before re-writes
  {
    const float2 wstep = twid((uint32_t)(c + 256*mL) & 0xFFFFu, UNIT64K, +1.0f);
    float2 w = wstep;
    __half2 hv[16];
    hv[0] = __floats2half2_rn(v[0].x, v[0].y);
#pragma unroll
    for (int kL2 = 1; kL2 < 16; kL2++){
      float2 y = cmul(v[kL2], w);
      w = cmul(w, wstep);
      hv[kL2] = __floats2half2_rn(y.x, y.y);
    }
    dft16h_inv(hv);                   // x[mL+16mH] at hv[sw4(mH)]
    __half2* BR = buf + row*RPW;
#pragma unroll
    for (int mH = 0; mH < 8; mH++)    // keep m<128 only
      BR[mL + 20*mH] = hv[sw4(mH)];
  }
  __syncthreads();
  // ---- epilogue: softmax mix + tanh + atomicAdd --------------------------
  const float gv = fabsf(gains[r]);
#pragma unroll
  for (int it = 0; it < 4; it++){
    const int li = t + it*256;        // li = m*8 + cc2, m < 128
    const int cc2 = li & 7, m = li >> 3;
    const int tt = c0 + cc2 + 256*m;
    int lo, hi; float w;
    interp128(tt, lo, hi, w);
    const int cell = (m & 15) + 20*(m >> 4);   // SKP(m)
    float2 z0 = __half22float2(buf[cc2*RPW + cell]);
    float2 z1 = __half22float2(buf[(8 + cc2)*RPW + cell]);
    float dw0 = sm_lds[0*128 + lo]*(1.0f - w) + sm_lds[0*128 + hi]*w;
    float dw1 = sm_lds[1*128 + lo]*(1.0f - w) + sm_lds[1*128 + hi]*w;
    float dw2 = sm_lds[2*128 + lo]*(1.0f - w) + sm_lds[2*128 + hi]*w;
    float dw3 = sm_lds[3*128 + lo]*(1.0f - w) + sm_lds[3*128 + hi]*w;
    float val = dw0*z0.x + dw1*z0.y + dw2*z1.x + dw3*z1.y;  // scale pre-folded
    atomicAdd(&out0[(size_t)be*32768 + tt], tanhf(val*gv));
  }
}

extern "C" void kernel_launch(void* const* d_in, const int* in_sizes, int n_in,
                              void* d_out, int out_size, void* d_ws, size_t ws_size,
                              hipStream_t stream){
  const float* ctrl   = (const float*)d_in[0];
  const float* defm   = (const float*)d_in[1];
  const float* router = (const float*)d_in[2];
  const float* amp    = (const float*)d_in[3];
  const float* phase  = (const float*)d_in[4];
  const float* decay  = (const float*)d_in[5];
  const float* gains  = (const float*)d_in[6];
  float* out = (float*)d_out;
  float* ws  = (float*)d_ws;

  // ws layout (float offsets)
  float*   w_resT    = ws;                          // 4,194,304 (dead after
                                                    // fwdA m0 -> reused as resp_t)
  float*   w_routed  = ws + 4194304;                // 32,768
  float*   w_sm      = ws + 4227072;                // 4,096
  float*   w_invnorm = ws + 4231168;                // 128
  float*   w_sumsq   = ws + 4231296;                // 128
  __half2* ruspec_h  = (__half2*)(ws + 4231424);    // 256*65536 h2 = 16,777,216 f
  __half2* resp_h    = (__half2*)(ws + 21008640);   // 64*65536 h2  =  4,194,304 f
  __half2* chunk_h   = (__half2*)(ws + 25202944);   // 2G*65536 h2  = G*131,072 f
  const size_t base_f = 25202944;
  // frames scratch aliases ruspec_h region (ruspec written later by fwdA)
  float2* w_fr       = (float2*)ruspec_h;           // 2048*2048 c = 8,388,608 f
  // resp_t (k_conv-order res spectra) reuses w_resT: 64*65536 h2 = 16MB exact
  __half2* resp_t    = (__half2*)w_resT;
  // pql (k_prep output) aliases resp_h: consumed before fwdA m0 writes it
  float4*  pql       = (float4*)resp_h;

  int G = 0;
  for (int gg = 256; gg >= 1; gg >>= 1){
    size_t need = (base_f + (size_t)gg*131072) * sizeof(float);
    if (need <= ws_size){ G = gg; break; }
  }

  hipMemsetAsync(d_out, 0, 262144*sizeof(float), stream);  // out0 (atomicAdd)
  k_routed<<<132, 256, 0, stream>>>(ctrl, defm, router, w_routed, w_sm, out + 262144);
  if (G == 0) return;  // diagnostic: out1 ok, out0 stays 0 => ws too small

  hipMemsetAsync(w_sumsq, 0, 128*sizeof(float), stream);
  k_prep<<<513, 256, 0, stream>>>(amp, phase, decay, pql);
  k_frames<<<2048, 256, 0, stream>>>(pql, w_fr);
  k_ola<<<512, 256, 0, stream>>>(w_fr, w_resT, w_sumsq);
  k_norm<<<1, 128, 0, stream>>>(w_sumsq, w_invnorm);
  k_fwdA<<<64*16, 256, 0, stream>>>(0, w_resT, w_invnorm, w_routed, resp_h);
  k_fwdB<<<64*16, 256, 0, stream>>>(resp_h, resp_t);
  k_fwdA<<<256*16, 256, 0, stream>>>(1, w_resT, w_invnorm, w_routed, ruspec_h);
  for (int gb = 0; gb < 256; gb += G){
    const int remap = (G == 256) ? 1 : 0;
    k_conv<<<G*16, 256, 0, stream>>>(ruspec_h, resp_t, chunk_h, gb, remap);
    k_invA_w<<<G*32, 256, 0, stream>>>(chunk_h, gb, w_sm, gains, out);
  }
}